// Round 8
// baseline (17379.630 us; speedup 1.0000x reference)
//
#include <hip/hip_runtime.h>

typedef unsigned short ushort_t;
typedef unsigned int uint_t;
typedef unsigned long long u64;
typedef __attribute__((ext_vector_type(8))) short short8;
typedef __attribute__((ext_vector_type(4))) float floatx4;

#define S_LEN 1024
#define BATCH 32
#define HDIM  256
#define GDIM  1024  /* 4H */
#define DIN   128

__device__ __forceinline__ float bf2f(ushort_t u) { return __uint_as_float(((unsigned)u) << 16); }
__device__ __forceinline__ float bf2fs(short s)   { return __uint_as_float(((unsigned)(unsigned short)s) << 16); }
__device__ __forceinline__ ushort_t f2bf(float f) {
  unsigned u = __float_as_uint(f);
  unsigned r = (u + 0x7fffu + ((u >> 16) & 1u)) >> 16;
  return (ushort_t)r;
}
__device__ __forceinline__ float sigf(float x) { return 1.f / (1.f + __expf(-x)); }
__device__ __forceinline__ float tanh_f(float x) {
  float ax = fabsf(x);
  float e = __expf(2.f * ax);
  float r = 1.f - 2.f / (e + 1.f);
  return x < 0.f ? -r : r;
}

__device__ __forceinline__ void load_lds16(const void* g, void* l) {
  __builtin_amdgcn_global_load_lds((const __attribute__((address_space(1))) unsigned int*)g,
                                   (__attribute__((address_space(3))) unsigned int*)l, 16, 0, 0);
}

// LDS-only barrier: drains lgkm (LDS ops) but NOT vmcnt, so in-flight global
// prefetches (ldxp) and fire-and-forget stores (hout) stay in flight.
// sched_barrier fences prevent hipcc from hoisting LDS ops across (rule #18).
__device__ __forceinline__ void lds_barrier() {
  __builtin_amdgcn_sched_barrier(0);
  asm volatile("s_waitcnt lgkmcnt(0)" ::: "memory");
  __builtin_amdgcn_s_barrier();
  __builtin_amdgcn_sched_barrier(0);
}

// ---------------------------------------------------------------------------
// Generic bf16 MFMA GEMM: C[m][n] = sum_k A[m][k]*B[n][k] + bias[n]
// mode 0: bf16 at C[m*N+n]          (h layout [t][b][n], m = t*32+b)
// mode 1: fp32 at out[b][t][n]      (head output)
// mode 2: bf16 at C[t][n][b]        (xp transposed for vectorized recurrence)
// ---------------------------------------------------------------------------
__global__ __launch_bounds__(256) void gemm_bf16(
    const ushort_t* __restrict__ A, const ushort_t* __restrict__ Bw,
    const float* __restrict__ bias, void* __restrict__ Cout,
    int M, int N, int K, int mode)
{
  __shared__ __align__(16) ushort_t As[128 * 64];
  __shared__ __align__(16) ushort_t Bs[128 * 64];
  const int tid = threadIdx.x;
  const int lane = tid & 63, wid = tid >> 6;
  const int wm = wid >> 1, wn = wid & 1;
  const int bm = blockIdx.y, bn = blockIdx.x;
  const int l15 = lane & 15, q4 = lane >> 4;

  const int r  = tid >> 3;
  const int c8 = tid & 7;
  const int g8 = c8 ^ (r & 7);

  floatx4 zero4 = {0.f, 0.f, 0.f, 0.f};
  floatx4 acc[4][4];
#pragma unroll
  for (int mt = 0; mt < 4; ++mt)
#pragma unroll
    for (int nt = 0; nt < 4; ++nt) acc[mt][nt] = zero4;

  for (int k0 = 0; k0 < K; k0 += 64) {
    __syncthreads();
#pragma unroll
    for (int p = 0; p < 4; ++p) {
      int row = p * 32 + r;
      load_lds16(A + (size_t)(bm * 128 + row) * K + k0 + g8 * 8, (void*)(As + p * 2048 + wid * 512));
      load_lds16(Bw + (size_t)(bn * 128 + row) * K + k0 + g8 * 8, (void*)(Bs + p * 2048 + wid * 512));
    }
    __syncthreads();
#pragma unroll
    for (int ks = 0; ks < 2; ++ks) {
      const int kk = ks * 4 + q4;
      short8 af[4], bf[4];
#pragma unroll
      for (int mt = 0; mt < 4; ++mt) {
        int row = wm * 64 + mt * 16 + l15;
        af[mt] = *(const short8*)(As + row * 64 + ((kk ^ (row & 7)) << 3));
      }
#pragma unroll
      for (int nt = 0; nt < 4; ++nt) {
        int row = wn * 64 + nt * 16 + l15;
        bf[nt] = *(const short8*)(Bs + row * 64 + ((kk ^ (row & 7)) << 3));
      }
#pragma unroll
      for (int mt = 0; mt < 4; ++mt)
#pragma unroll
        for (int nt = 0; nt < 4; ++nt)
          acc[mt][nt] = __builtin_amdgcn_mfma_f32_16x16x32_bf16(af[mt], bf[nt], acc[mt][nt], 0, 0, 0);
    }
  }

#pragma unroll
  for (int mt = 0; mt < 4; ++mt)
#pragma unroll
    for (int nt = 0; nt < 4; ++nt)
#pragma unroll
      for (int rr = 0; rr < 4; ++rr) {
        int m = bm * 128 + wm * 64 + mt * 16 + q4 * 4 + rr;
        int n = bn * 128 + wn * 64 + nt * 16 + l15;
        float v = acc[mt][nt][rr] + bias[n];
        if (mode == 0) {
          ((ushort_t*)Cout)[(size_t)m * N + n] = f2bf(v);
        } else if (mode == 1) {
          int t = m >> 5, b = m & 31;
          ((float*)Cout)[(size_t)b * (S_LEN * DIN) + t * DIN + n] = v;
        } else {
          int t = m >> 5, b = m & 31;
          ((ushort_t*)Cout)[(size_t)t * (N * 32) + n * 32 + b] = f2bf(v);
        }
      }
}

// ---------------------------------------------------------------------------
// Bidirectional LSTM recurrence — BATCH-PARALLEL, ZERO inter-WG communication.
//
// KEY INSIGHT (R7 post-mortem): h_t[b] depends only on h_{t-1}[b] — batches
// never interact in the recurrence. R0-R7 split the HIDDEN dim across WGs and
// paid ~3 device-scope MALL round trips (~6700 cy) per step for the exchange;
// that loop latency was invariant to every scheduling trick (R4=R6=R7=3430us).
// Splitting the BATCH dim removes the chip from the dependency loop entirely.
//
// Grid = 4 WGs x 1024 threads: dir = bx&1, bg = bx>>1 (16-batch group).
// Per WG: gates[16 x 1024] = xp + h[16 x 256] @ Whh^T, all in one CU:
//  * wave w (0..15) owns gate rows {gg*256 + w*16 + l15, gg=0..3}: all FOUR
//    gates for h-cols w*16..w*16+15. MFMA C-layout (col=lane&15,
//    row=q4*4+rr) puts i,f,g,o for (batch,col) in the SAME lane ->
//    register-local cell, no stage, no shuffles.
//  * Whh in registers: Bf[4][8] = 128 VGPRs/wave (64 rows x 256 K / 64 lanes).
//  * h double-buffered in LDS (hbuf[2], 8.4 KB each); ONE lgkm-only barrier
//    per step (cell writes buf[nxt] while MFMA read buf[cur]; no WAR).
//    NO __syncthreads in the loop (it would drain the hout stores).
//  * per-step: 32 MFMAs/wave -> per SIMD 128 x ~19.4cy ~= 2500 cy issue-bound;
//    sigmoid/tanh (~1300 cy trans) overlaps on the VALU/trans pipe (m114).
//  * xp prefetched 1 step ahead into registers (used ~3000 cy later); the
//    only vm wait is a counted vmcnt on the 4 xp loads (hout store younger,
//    never drained).
//  * xpad (64 KB) caps occupancy at 1 WG/CU so two WGs never share a CU's
//    MFMA pipe. Referenced via never-true runtime condition to defeat DCE.
//
// No comm buffers, no epochs, no atomics, no spin loops -> deterministic,
// trivially graph-replay safe.
// ---------------------------------------------------------------------------
__global__ __launch_bounds__(1024, 1) void lstm_layer(
    const ushort_t* __restrict__ xpf, const ushort_t* __restrict__ xpb,
    const ushort_t* __restrict__ whhf, const ushort_t* __restrict__ whhb,
    ushort_t* __restrict__ hout)
{
  __shared__ __align__(16) ushort_t hbuf[2][16 * 264];  // h bf16 [batch][col], stride 264
  __shared__ __align__(16) char xpad[64 * 1024];        // occupancy limiter: 1 WG/CU

  const int bx = blockIdx.x;
  const int dir = bx & 1, bg = bx >> 1;

  const ushort_t* xp  = dir ? xpb : xpf;
  const ushort_t* whh = dir ? whhb : whhf;
  const int hoff = dir * 256;
  const int boff = bg * 16;

  const int tid = threadIdx.x, lane = tid & 63, w = tid >> 6;  // w in 0..15
  const int l15 = lane & 15, q4 = lane >> 4;

  if (blockDim.x == 0) ((volatile char*)xpad)[0] = 1;  // never true; keeps xpad alive

  // permanent B-fragments: wave w, gate gg -> gate row gg*256 + w*16 + l15
  short8 Bf[4][8];
#pragma unroll
  for (int gg = 0; gg < 4; ++gg) {
    int grow = gg * 256 + w * 16 + l15;
#pragma unroll
    for (int ks = 0; ks < 8; ++ks)
      Bf[gg][ks] = *(const short8*)(whh + (size_t)grow * 256 + ks * 32 + q4 * 8);
  }

  // zero buf0: h_{-1} = 0
  for (int i = tid; i < 16 * 132; i += 1024) ((uint_t*)hbuf[0])[i] = 0u;

  float cst[4] = {0.f, 0.f, 0.f, 0.f};

  // xp: [t][g][b] layout; one u64 = 4 consecutive batches of this WG's group
  u64 xr64[4];
  auto ldxp = [&](int tt) {
#pragma unroll
    for (int gg = 0; gg < 4; ++gg) {
      int g = gg * 256 + w * 16 + l15;
      xr64[gg] = *(const u64*)(xp + (size_t)tt * (GDIM * BATCH) + (size_t)g * 32 + boff + q4 * 4);
    }
  };

  ldxp((dir == 0) ? 0 : 1023);
  lds_barrier();

  const int hr = tid >> 6;   // hout writer: local batch row 0..15
  const int hc = tid & 63;   // hout writer: 4-col group 0..63

  for (int sc = 0; sc < 1024; ++sc) {
    const int tcur  = (dir == 0) ? sc : 1023 - sc;
    const int tnext = (dir == 0) ? (sc < 1023 ? sc + 1 : 1023) : (sc < 1023 ? 1022 - sc : 0);
    const ushort_t* hb_c = hbuf[sc & 1];
    ushort_t* hb_n = hbuf[(sc + 1) & 1];

    // gates init = xp (counted vmcnt wait on 4 loads issued last step; the
    // younger hout store stays in flight)
    floatx4 acc[4];
#pragma unroll
    for (int gg = 0; gg < 4; ++gg) {
      u64 v = xr64[gg];
#pragma unroll
      for (int rr = 0; rr < 4; ++rr)
        acc[gg][rr] = bf2f((ushort_t)(v >> (16 * rr)));
    }
    ldxp(tnext);  // prefetch next step (hidden under MFMA + cell)

    // gates += h_{t-1} @ whh^T : 32 MFMAs/wave, A-frags from LDS
#pragma unroll
    for (int ks = 0; ks < 8; ++ks) {
      short8 a = *(const short8*)(hb_c + l15 * 264 + ks * 32 + q4 * 8);
#pragma unroll
      for (int gg = 0; gg < 4; ++gg)
        acc[gg] = __builtin_amdgcn_mfma_f32_16x16x32_bf16(a, Bf[gg][ks], acc[gg], 0, 0, 0);
    }

    // register-local LSTM cell: lane owns (col = w*16+l15, batches q4*4+rr);
    // acc[0]=i, acc[1]=f, acc[2]=g, acc[3]=o (PyTorch gate order)
#pragma unroll
    for (int rr = 0; rr < 4; ++rr) {
      float c = sigf(acc[1][rr]) * cst[rr] + sigf(acc[0][rr]) * tanh_f(acc[2][rr]);
      cst[rr] = c;
      float hv = sigf(acc[3][rr]) * tanh_f(c);
      hb_n[(q4 * 4 + rr) * 264 + w * 16 + l15] = f2bf(hv);
    }

    lds_barrier();  // h_t complete in hb_n; hout store below NOT drained here

    // hout: one coalesced u64 per thread from hb_n (read-read with next
    // step's MFMA on hb_n; next step's cell writes go to hb_c — no race)
    u64 hv64 = *(const u64*)(hb_n + hr * 264 + hc * 4);
    *(u64*)(hout + (size_t)tcur * (BATCH * 512) + (size_t)(boff + hr) * 512 + hoff + hc * 4) = hv64;
  }
}

// ---------------------------------------------------------------------------
// Attention scores -> e = exp(s - max_t s), per batch b.
// ---------------------------------------------------------------------------
__global__ __launch_bounds__(256) void attn_scores(
    const ushort_t* __restrict__ h1, const float* __restrict__ attn_w,
    const float* __restrict__ attn_b, float* __restrict__ e_out)
{
  const int b = blockIdx.x;
  __shared__ float sbuf[1024];
  __shared__ float red[4];
  const int tid = threadIdx.x, lane = tid & 63, w = tid >> 6;

  float wreg[8];
#pragma unroll
  for (int i = 0; i < 8; ++i) wreg[i] = attn_w[lane * 8 + i];

  for (int t = w; t < 1024; t += 4) {
    short8 hv = *(const short8*)(h1 + (size_t)t * (BATCH * 512) + b * 512 + lane * 8);
    float dot = 0.f;
#pragma unroll
    for (int i = 0; i < 8; ++i) dot += bf2fs(hv[i]) * wreg[i];
#pragma unroll
    for (int off = 32; off; off >>= 1) dot += __shfl_xor(dot, off);
    if (lane == 0) sbuf[t] = dot + attn_b[0];
  }
  __syncthreads();
  float m = -1e30f;
  for (int t = tid; t < 1024; t += 256) m = fmaxf(m, sbuf[t]);
#pragma unroll
  for (int off = 32; off; off >>= 1) m = fmaxf(m, __shfl_xor(m, off));
  if (lane == 0) red[w] = m;
  __syncthreads();
  float mm = fmaxf(fmaxf(red[0], red[1]), fmaxf(red[2], red[3]));
  for (int t = tid; t < 1024; t += 256) e_out[b * 1024 + t] = __expf(sbuf[t] - mm);
}

// ---------------------------------------------------------------------------
// Cumulative context: ctx[t][b][c] = (sum_{u<=t} e_u h_u[c]) / (sum e_u), bf16.
// ---------------------------------------------------------------------------
__global__ __launch_bounds__(256) void attn_ctx(
    const ushort_t* __restrict__ h1, const float* __restrict__ e_in, ushort_t* __restrict__ ctx)
{
  const int b = blockIdx.x >> 1, half = blockIdx.x & 1;
  const int c = half * 256 + threadIdx.x;
  float num = 0.f, den = 0.f;
  const ushort_t* hp = h1 + b * 512 + c;
  ushort_t* cp = ctx + b * 512 + c;
  const float* ep = e_in + b * 1024;
#pragma unroll 4
  for (int t = 0; t < 1024; ++t) {
    float ev = ep[t];
    float hv = bf2f(hp[(size_t)t * (BATCH * 512)]);
    num += ev * hv;
    den += ev;
    cp[(size_t)t * (BATCH * 512)] = f2bf(num / den);
  }
}

// ---------------------------------------------------------------------------
// casts
// ---------------------------------------------------------------------------
__global__ void castw(const float* __restrict__ in, ushort_t* __restrict__ out, int n) {
  int i = blockIdx.x * 256 + threadIdx.x;
  if (i < n) out[i] = f2bf(in[i]);
}
__global__ void castx(const float* __restrict__ x, ushort_t* __restrict__ xt) {
  int i = blockIdx.x * 256 + threadIdx.x;  // over 32768*128
  int dcol = i & 127;
  int m = i >> 7;
  int b = m & 31, s = m >> 5;
  xt[i] = f2bf(x[(size_t)b * (S_LEN * DIN) + s * DIN + dcol]);
}

extern "C" void kernel_launch(void* const* d_in, const int* in_sizes, int n_in,
                              void* d_out, int out_size, void* d_ws, size_t ws_size,
                              hipStream_t stream)
{
  const float* x     = (const float*)d_in[0];
  const float* wih0f = (const float*)d_in[1];
  const float* whh0f = (const float*)d_in[2];
  const float* b0f   = (const float*)d_in[3];
  const float* wih0b = (const float*)d_in[4];
  const float* whh0b = (const float*)d_in[5];
  const float* b0b   = (const float*)d_in[6];
  const float* wih1f = (const float*)d_in[7];
  const float* whh1f = (const float*)d_in[8];
  const float* b1f   = (const float*)d_in[9];
  const float* wih1b = (const float*)d_in[10];
  const float* whh1b = (const float*)d_in[11];
  const float* b1b   = (const float*)d_in[12];
  const float* attw  = (const float*)d_in[13];
  const float* attb  = (const float*)d_in[14];
  const float* headw = (const float*)d_in[15];
  const float* headb = (const float*)d_in[16];
  float* out = (float*)d_out;

  char* p = (char*)d_ws;
  auto alloc = [&](size_t bytes) {
    char* r = p;
    p += (bytes + 511) & ~(size_t)511;
    return r;
  };
  ushort_t* xt    = (ushort_t*)alloc((size_t)32768 * 128 * 2);
  ushort_t* cwih0f = (ushort_t*)alloc(131072 * 2);
  ushort_t* cwih0b = (ushort_t*)alloc(131072 * 2);
  ushort_t* cwhh0f = (ushort_t*)alloc(262144 * 2);
  ushort_t* cwhh0b = (ushort_t*)alloc(262144 * 2);
  ushort_t* cwih1f = (ushort_t*)alloc(524288 * 2);
  ushort_t* cwih1b = (ushort_t*)alloc(524288 * 2);
  ushort_t* cwhh1f = (ushort_t*)alloc(262144 * 2);
  ushort_t* cwhh1b = (ushort_t*)alloc(262144 * 2);
  ushort_t* cwhead = (ushort_t*)alloc(65536 * 2);
  ushort_t* xpA = (ushort_t*)alloc((size_t)32768 * 1024 * 2);
  ushort_t* xpB = (ushort_t*)alloc((size_t)32768 * 1024 * 2);
  ushort_t* h0  = (ushort_t*)alloc((size_t)32768 * 512 * 2);
  ushort_t* h1  = (ushort_t*)alloc((size_t)32768 * 512 * 2);
  float* ebuf   = (float*)alloc(32 * 1024 * 4);
  ushort_t* ctx = xpA;  // reuse (xp dead by then)

  (void)in_sizes; (void)n_in; (void)out_size; (void)ws_size;

  // no sync state anymore: no memset needed (batch-parallel recurrence)

  castw<<<512, 256, 0, stream>>>(wih0f, cwih0f, 131072);
  castw<<<512, 256, 0, stream>>>(wih0b, cwih0b, 131072);
  castw<<<1024, 256, 0, stream>>>(whh0f, cwhh0f, 262144);
  castw<<<1024, 256, 0, stream>>>(whh0b, cwhh0b, 262144);
  castw<<<2048, 256, 0, stream>>>(wih1f, cwih1f, 524288);
  castw<<<2048, 256, 0, stream>>>(wih1b, cwih1b, 524288);
  castw<<<1024, 256, 0, stream>>>(whh1f, cwhh1f, 262144);
  castw<<<1024, 256, 0, stream>>>(whh1b, cwhh1b, 262144);
  castw<<<256, 256, 0, stream>>>(headw, cwhead, 65536);
  castx<<<16384, 256, 0, stream>>>(x, xt);

  // layer 0: xp in transposed [t][g][b] layout (mode 2)
  gemm_bf16<<<dim3(8, 256), 256, 0, stream>>>(xt, cwih0f, b0f, xpA, 32768, 1024, 128, 2);
  gemm_bf16<<<dim3(8, 256), 256, 0, stream>>>(xt, cwih0b, b0b, xpB, 32768, 1024, 128, 2);
  lstm_layer<<<4, 1024, 0, stream>>>(xpA, xpB, cwhh0f, cwhh0b, h0);

  // layer 1
  gemm_bf16<<<dim3(8, 256), 256, 0, stream>>>(h0, cwih1f, b1f, xpA, 32768, 1024, 512, 2);
  gemm_bf16<<<dim3(8, 256), 256, 0, stream>>>(h0, cwih1b, b1b, xpB, 32768, 1024, 512, 2);
  lstm_layer<<<4, 1024, 0, stream>>>(xpA, xpB, cwhh1f, cwhh1b, h1);

  // attention + head
  attn_scores<<<32, 256, 0, stream>>>(h1, attw, attb, ebuf);
  attn_ctx<<<64, 256, 0, stream>>>(h1, ebuf, ctx);
  gemm_bf16<<<dim3(1, 256), 256, 0, stream>>>(ctx, cwhead, headb, out, 32768, 128, 512, 1);
}

// Round 9
// 10971.236 us; speedup vs baseline: 1.5841x; 1.5841x over previous
//
#include <hip/hip_runtime.h>

typedef unsigned short ushort_t;
typedef unsigned int uint_t;
typedef unsigned long long u64;
typedef __attribute__((ext_vector_type(8))) short short8;
typedef __attribute__((ext_vector_type(4))) float floatx4;

#define S_LEN 1024
#define BATCH 32
#define HDIM  256
#define GDIM  1024  /* 4H */
#define DIN   128

__device__ __forceinline__ float bf2f(ushort_t u) { return __uint_as_float(((unsigned)u) << 16); }
__device__ __forceinline__ float bf2fs(short s)   { return __uint_as_float(((unsigned)(unsigned short)s) << 16); }
__device__ __forceinline__ ushort_t f2bf(float f) {
  unsigned u = __float_as_uint(f);
  unsigned r = (u + 0x7fffu + ((u >> 16) & 1u)) >> 16;
  return (ushort_t)r;
}
__device__ __forceinline__ float sigf(float x) { return 1.f / (1.f + __expf(-x)); }
__device__ __forceinline__ float tanh_f(float x) {
  float ax = fabsf(x);
  float e = __expf(2.f * ax);
  float r = 1.f - 2.f / (e + 1.f);
  return x < 0.f ? -r : r;
}

__device__ __forceinline__ void load_lds16(const void* g, void* l) {
  __builtin_amdgcn_global_load_lds((const __attribute__((address_space(1))) unsigned int*)g,
                                   (__attribute__((address_space(3))) unsigned int*)l, 16, 0, 0);
}

// LDS-only barrier: drains lgkm (LDS ops) but NOT vmcnt, so in-flight global
// prefetches (ldxp, o-stream) and fire-and-forget stores (hout) stay in
// flight. sched_barrier fences prevent hipcc hoisting LDS ops across.
__device__ __forceinline__ void lds_barrier() {
  __builtin_amdgcn_sched_barrier(0);
  asm volatile("s_waitcnt lgkmcnt(0)" ::: "memory");
  __builtin_amdgcn_s_barrier();
  __builtin_amdgcn_sched_barrier(0);
}

// ---------------------------------------------------------------------------
// Generic bf16 MFMA GEMM: C[m][n] = sum_k A[m][k]*B[n][k] + bias[n]
// mode 0: bf16 at C[m*N+n]          (h layout [t][b][n], m = t*32+b)
// mode 1: fp32 at out[b][t][n]      (head output)
// mode 2: bf16 at C[t][n][b]        (xp transposed for vectorized recurrence)
// ---------------------------------------------------------------------------
__global__ __launch_bounds__(256) void gemm_bf16(
    const ushort_t* __restrict__ A, const ushort_t* __restrict__ Bw,
    const float* __restrict__ bias, void* __restrict__ Cout,
    int M, int N, int K, int mode)
{
  __shared__ __align__(16) ushort_t As[128 * 64];
  __shared__ __align__(16) ushort_t Bs[128 * 64];
  const int tid = threadIdx.x;
  const int lane = tid & 63, wid = tid >> 6;
  const int wm = wid >> 1, wn = wid & 1;
  const int bm = blockIdx.y, bn = blockIdx.x;
  const int l15 = lane & 15, q4 = lane >> 4;

  const int r  = tid >> 3;
  const int c8 = tid & 7;
  const int g8 = c8 ^ (r & 7);

  floatx4 zero4 = {0.f, 0.f, 0.f, 0.f};
  floatx4 acc[4][4];
#pragma unroll
  for (int mt = 0; mt < 4; ++mt)
#pragma unroll
    for (int nt = 0; nt < 4; ++nt) acc[mt][nt] = zero4;

  for (int k0 = 0; k0 < K; k0 += 64) {
    __syncthreads();
#pragma unroll
    for (int p = 0; p < 4; ++p) {
      int row = p * 32 + r;
      load_lds16(A + (size_t)(bm * 128 + row) * K + k0 + g8 * 8, (void*)(As + p * 2048 + wid * 512));
      load_lds16(Bw + (size_t)(bn * 128 + row) * K + k0 + g8 * 8, (void*)(Bs + p * 2048 + wid * 512));
    }
    __syncthreads();
#pragma unroll
    for (int ks = 0; ks < 2; ++ks) {
      const int kk = ks * 4 + q4;
      short8 af[4], bf[4];
#pragma unroll
      for (int mt = 0; mt < 4; ++mt) {
        int row = wm * 64 + mt * 16 + l15;
        af[mt] = *(const short8*)(As + row * 64 + ((kk ^ (row & 7)) << 3));
      }
#pragma unroll
      for (int nt = 0; nt < 4; ++nt) {
        int row = wn * 64 + nt * 16 + l15;
        bf[nt] = *(const short8*)(Bs + row * 64 + ((kk ^ (row & 7)) << 3));
      }
#pragma unroll
      for (int mt = 0; mt < 4; ++mt)
#pragma unroll
        for (int nt = 0; nt < 4; ++nt)
          acc[mt][nt] = __builtin_amdgcn_mfma_f32_16x16x32_bf16(af[mt], bf[nt], acc[mt][nt], 0, 0, 0);
    }
  }

#pragma unroll
  for (int mt = 0; mt < 4; ++mt)
#pragma unroll
    for (int nt = 0; nt < 4; ++nt)
#pragma unroll
      for (int rr = 0; rr < 4; ++rr) {
        int m = bm * 128 + wm * 64 + mt * 16 + q4 * 4 + rr;
        int n = bn * 128 + wn * 64 + nt * 16 + l15;
        float v = acc[mt][nt][rr] + bias[n];
        if (mode == 0) {
          ((ushort_t*)Cout)[(size_t)m * N + n] = f2bf(v);
        } else if (mode == 1) {
          int t = m >> 5, b = m & 31;
          ((float*)Cout)[(size_t)b * (S_LEN * DIN) + t * DIN + n] = v;
        } else {
          int t = m >> 5, b = m & 31;
          ((ushort_t*)Cout)[(size_t)t * (N * 32) + n * 32 + b] = f2bf(v);
        }
      }
}

// ---------------------------------------------------------------------------
// Bidirectional LSTM recurrence — batch-parallel (zero inter-WG comm), with
// 3-TIER WEIGHT RESIDENCY fixing R8's register-spill catastrophe.
//
// R8 lesson: register-resident Whh at 16 waves = exactly the 128-reg budget
// (512KB / 16 waves / 64 lanes), leaving nothing for the working set -> the
// compiler spilled the hot weights (VGPR=64, 19.5kcy/step). Fix: 8 waves
// (512 thr, 2 waves/SIMD -> 256 regs/wave) and split Whh by gate:
//   * i,f gates (rows 0..511) in REGISTERS: 2 gates x 2 tiles x 8 frags
//     = 128 VGPRs.
//   * g gate (rows 512..767) in LDS [256][264] (132KB, padded stride ->
//     same 2-way bank profile as hbuf, proven benign in R4/R8).
//   * o gate (rows 768..1023) STREAMED from L2 each step (128KB/WG, fully
//     L2-resident after step 1) through a 2x16-reg half-buffer; half-2
//     loads pinned below half-1's MFMAs by sched_barrier(0) so the buffer
//     is reused, not renamed.
// Register demand ~246 <= 256; LDS 148.5KB -> naturally 1 WG/CU.
//
// Grid = 4 WGs x 512 threads: dir = bx&1, bg = bx>>1 (16-batch group).
// Wave w (0..7) owns h-cols w*32..w*32+31 (2 MFMA N-tiles) for ALL 4 gates
// -> MFMA C-layout (col=lane&15, row=q4*4+rr) puts i,f,g,o for (batch,col)
// in the SAME lane -> register-local cell, no stage, no shuffles.
//
// Load-issue order keeps every gating wait COUNTED (never a surprise
// vmcnt(0) on a fresh load): o-half1 issued BEFORE ldxp(tnext) so the
// o-wait is vmcnt(8) (xp stays in flight); the o-half2 wait doubles as the
// xp drain (~1500cy after issue -> mostly retired). One lgkm-only barrier
// per step. No __syncthreads in the loop (would drain hout stores).
// ---------------------------------------------------------------------------
__global__ __launch_bounds__(512, 2) void lstm_layer(
    const ushort_t* __restrict__ xpf, const ushort_t* __restrict__ xpb,
    const ushort_t* __restrict__ whhf, const ushort_t* __restrict__ whhb,
    ushort_t* __restrict__ hout)
{
  __shared__ __align__(16) ushort_t wg[256 * 264];     // g-gate weights, 132KB
  __shared__ __align__(16) ushort_t hbuf[2][16 * 264]; // h dbuf, 16.5KB

  const int bx = blockIdx.x;
  const int dir = bx & 1, bg = bx >> 1;

  const ushort_t* xp  = dir ? xpb : xpf;
  const ushort_t* whh = dir ? whhb : whhf;
  const int hoff = dir * 256;
  const int boff = bg * 16;

  const int tid = threadIdx.x, lane = tid & 63, w = tid >> 6;  // w in 0..7
  const int l15 = lane & 15, q4 = lane >> 4;

  // ---- prologue: g-gate -> LDS (padded stride 264) ----
  for (int idx = tid; idx < 256 * 32; idx += 512) {
    int row = idx >> 5, ch = idx & 31;
    *(short8*)(wg + row * 264 + ch * 8) =
        *(const short8*)(whh + (size_t)(512 + row) * 256 + ch * 8);
  }
  // zero hbuf[0]: h_{-1} = 0
  for (int i = tid; i < 16 * 132; i += 512) ((uint_t*)hbuf[0])[i] = 0u;

  // ---- permanent register fragments: i (rows 0..255), f (rows 256..511) ----
  short8 Bfi[2][8], Bff[2][8];
#pragma unroll
  for (int tl = 0; tl < 2; ++tl) {
    int rbase = w * 32 + tl * 16 + l15;
#pragma unroll
    for (int ks = 0; ks < 8; ++ks) {
      Bfi[tl][ks] = *(const short8*)(whh + (size_t)(rbase)       * 256 + ks * 32 + q4 * 8);
      Bff[tl][ks] = *(const short8*)(whh + (size_t)(256 + rbase) * 256 + ks * 32 + q4 * 8);
    }
  }

  // o-gate stream bases (rows 768..1023), per lane, per tile
  const ushort_t* ob0 = whh + (size_t)(768 + w * 32 + l15) * 256 + q4 * 8;
  const ushort_t* ob1 = ob0 + (size_t)16 * 256;

  float cst[2][4];
#pragma unroll
  for (int tl = 0; tl < 2; ++tl)
#pragma unroll
    for (int rr = 0; rr < 4; ++rr) cst[tl][rr] = 0.f;

  // xp: [t][g][b] layout; one u64 = 4 consecutive batches of this group
  u64 xr64[4][2];
  auto ldxp = [&](int tt) {
#pragma unroll
    for (int gg = 0; gg < 4; ++gg)
#pragma unroll
      for (int tl = 0; tl < 2; ++tl) {
        int g = gg * 256 + w * 32 + tl * 16 + l15;
        xr64[gg][tl] = *(const u64*)(xp + (size_t)tt * (GDIM * BATCH) + (size_t)g * 32 + boff + q4 * 4);
      }
  };

  ldxp((dir == 0) ? 0 : 1023);
  __syncthreads();  // prologue only: wg + hbuf[0] ready

  const int hr = tid >> 5;   // hout: local batch row 0..15
  const int hc = tid & 31;   // hout: 8-col group 0..31

  for (int sc = 0; sc < 1024; ++sc) {
    const int tcur  = (dir == 0) ? sc : 1023 - sc;
    const int tnext = (dir == 0) ? (sc < 1023 ? sc + 1 : 1023) : (sc < 1023 ? 1022 - sc : 0);
    const ushort_t* hb_c = hbuf[sc & 1];
    ushort_t* hb_n = hbuf[(sc + 1) & 1];

    // gates init = xp (counted vmcnt wait on xp loads issued last step)
    floatx4 acc[4][2];
#pragma unroll
    for (int gg = 0; gg < 4; ++gg)
#pragma unroll
      for (int tl = 0; tl < 2; ++tl) {
        u64 v = xr64[gg][tl];
#pragma unroll
        for (int rr = 0; rr < 4; ++rr)
          acc[gg][tl][rr] = bf2f((ushort_t)(v >> (16 * rr)));
      }

    // o-gate half-1 issue (BEFORE ldxp so its wait is vmcnt(8), not 0)
    short8 of[2][4];
#pragma unroll
    for (int k = 0; k < 4; ++k) {
      of[0][k] = *(const short8*)(ob0 + k * 32);
      of[1][k] = *(const short8*)(ob1 + k * 32);
    }

    ldxp(tnext);  // next step's xp; drains at o-half2 wait (~1500cy later)

    // ---- pass 1: i, f (regs) + g (LDS) ----
#pragma unroll
    for (int ks = 0; ks < 8; ++ks) {
      short8 a = *(const short8*)(hb_c + l15 * 264 + ks * 32 + q4 * 8);
      short8 g0 = *(const short8*)(wg + (w * 32 + l15) * 264 + ks * 32 + q4 * 8);
      short8 g1 = *(const short8*)(wg + (w * 32 + 16 + l15) * 264 + ks * 32 + q4 * 8);
      acc[0][0] = __builtin_amdgcn_mfma_f32_16x16x32_bf16(a, Bfi[0][ks], acc[0][0], 0, 0, 0);
      acc[0][1] = __builtin_amdgcn_mfma_f32_16x16x32_bf16(a, Bfi[1][ks], acc[0][1], 0, 0, 0);
      acc[1][0] = __builtin_amdgcn_mfma_f32_16x16x32_bf16(a, Bff[0][ks], acc[1][0], 0, 0, 0);
      acc[1][1] = __builtin_amdgcn_mfma_f32_16x16x32_bf16(a, Bff[1][ks], acc[1][1], 0, 0, 0);
      acc[2][0] = __builtin_amdgcn_mfma_f32_16x16x32_bf16(a, g0, acc[2][0], 0, 0, 0);
      acc[2][1] = __builtin_amdgcn_mfma_f32_16x16x32_bf16(a, g1, acc[2][1], 0, 0, 0);
    }

    // ---- o pass A (frags 0..3; waits o-half1, xp stays in flight) ----
#pragma unroll
    for (int ks = 0; ks < 4; ++ks) {
      short8 a = *(const short8*)(hb_c + l15 * 264 + ks * 32 + q4 * 8);
      acc[3][0] = __builtin_amdgcn_mfma_f32_16x16x32_bf16(a, of[0][ks], acc[3][0], 0, 0, 0);
      acc[3][1] = __builtin_amdgcn_mfma_f32_16x16x32_bf16(a, of[1][ks], acc[3][1], 0, 0, 0);
    }
    __builtin_amdgcn_sched_barrier(0);  // pin half-2 loads BELOW pass A (buffer reuse)
#pragma unroll
    for (int k = 0; k < 4; ++k) {
      of[0][k] = *(const short8*)(ob0 + (4 + k) * 32);
      of[1][k] = *(const short8*)(ob1 + (4 + k) * 32);
    }
#pragma unroll
    for (int ks = 4; ks < 8; ++ks) {
      short8 a = *(const short8*)(hb_c + l15 * 264 + ks * 32 + q4 * 8);
      acc[3][0] = __builtin_amdgcn_mfma_f32_16x16x32_bf16(a, of[0][ks - 4], acc[3][0], 0, 0, 0);
      acc[3][1] = __builtin_amdgcn_mfma_f32_16x16x32_bf16(a, of[1][ks - 4], acc[3][1], 0, 0, 0);
    }

    // ---- register-local LSTM cell: lane owns cols w*32+tl*16+l15,
    //      batches q4*4+rr; acc[0..3] = i,f,g,o (PyTorch order) ----
#pragma unroll
    for (int tl = 0; tl < 2; ++tl)
#pragma unroll
      for (int rr = 0; rr < 4; ++rr) {
        float c = sigf(acc[1][tl][rr]) * cst[tl][rr] + sigf(acc[0][tl][rr]) * tanh_f(acc[2][tl][rr]);
        cst[tl][rr] = c;
        float hv = sigf(acc[3][tl][rr]) * tanh_f(c);
        hb_n[(q4 * 4 + rr) * 264 + w * 32 + tl * 16 + l15] = f2bf(hv);
      }

    lds_barrier();  // h_t complete in hb_n; hout stores NOT drained here

    // hout: one coalesced 16B per thread (read-read with next step's MFMA
    // on hb_n; next step's cell writes go to hb_c — no race)
    short8 hv8 = *(const short8*)(hb_n + hr * 264 + hc * 8);
    *(short8*)(hout + (size_t)tcur * (BATCH * 512) + (size_t)(boff + hr) * 512 + hoff + hc * 8) = hv8;
  }
}

// ---------------------------------------------------------------------------
// Attention scores -> e = exp(s - max_t s), per batch b.
// ---------------------------------------------------------------------------
__global__ __launch_bounds__(256) void attn_scores(
    const ushort_t* __restrict__ h1, const float* __restrict__ attn_w,
    const float* __restrict__ attn_b, float* __restrict__ e_out)
{
  const int b = blockIdx.x;
  __shared__ float sbuf[1024];
  __shared__ float red[4];
  const int tid = threadIdx.x, lane = tid & 63, w = tid >> 6;

  float wreg[8];
#pragma unroll
  for (int i = 0; i < 8; ++i) wreg[i] = attn_w[lane * 8 + i];

  for (int t = w; t < 1024; t += 4) {
    short8 hv = *(const short8*)(h1 + (size_t)t * (BATCH * 512) + b * 512 + lane * 8);
    float dot = 0.f;
#pragma unroll
    for (int i = 0; i < 8; ++i) dot += bf2fs(hv[i]) * wreg[i];
#pragma unroll
    for (int off = 32; off; off >>= 1) dot += __shfl_xor(dot, off);
    if (lane == 0) sbuf[t] = dot + attn_b[0];
  }
  __syncthreads();
  float m = -1e30f;
  for (int t = tid; t < 1024; t += 256) m = fmaxf(m, sbuf[t]);
#pragma unroll
  for (int off = 32; off; off >>= 1) m = fmaxf(m, __shfl_xor(m, off));
  if (lane == 0) red[w] = m;
  __syncthreads();
  float mm = fmaxf(fmaxf(red[0], red[1]), fmaxf(red[2], red[3]));
  for (int t = tid; t < 1024; t += 256) e_out[b * 1024 + t] = __expf(sbuf[t] - mm);
}

// ---------------------------------------------------------------------------
// Cumulative context: ctx[t][b][c] = (sum_{u<=t} e_u h_u[c]) / (sum e_u), bf16.
// ---------------------------------------------------------------------------
__global__ __launch_bounds__(256) void attn_ctx(
    const ushort_t* __restrict__ h1, const float* __restrict__ e_in, ushort_t* __restrict__ ctx)
{
  const int b = blockIdx.x >> 1, half = blockIdx.x & 1;
  const int c = half * 256 + threadIdx.x;
  float num = 0.f, den = 0.f;
  const ushort_t* hp = h1 + b * 512 + c;
  ushort_t* cp = ctx + b * 512 + c;
  const float* ep = e_in + b * 1024;
#pragma unroll 4
  for (int t = 0; t < 1024; ++t) {
    float ev = ep[t];
    float hv = bf2f(hp[(size_t)t * (BATCH * 512)]);
    num += ev * hv;
    den += ev;
    cp[(size_t)t * (BATCH * 512)] = f2bf(num / den);
  }
}

// ---------------------------------------------------------------------------
// casts
// ---------------------------------------------------------------------------
__global__ void castw(const float* __restrict__ in, ushort_t* __restrict__ out, int n) {
  int i = blockIdx.x * 256 + threadIdx.x;
  if (i < n) out[i] = f2bf(in[i]);
}
__global__ void castx(const float* __restrict__ x, ushort_t* __restrict__ xt) {
  int i = blockIdx.x * 256 + threadIdx.x;  // over 32768*128
  int dcol = i & 127;
  int m = i >> 7;
  int b = m & 31, s = m >> 5;
  xt[i] = f2bf(x[(size_t)b * (S_LEN * DIN) + s * DIN + dcol]);
}

extern "C" void kernel_launch(void* const* d_in, const int* in_sizes, int n_in,
                              void* d_out, int out_size, void* d_ws, size_t ws_size,
                              hipStream_t stream)
{
  const float* x     = (const float*)d_in[0];
  const float* wih0f = (const float*)d_in[1];
  const float* whh0f = (const float*)d_in[2];
  const float* b0f   = (const float*)d_in[3];
  const float* wih0b = (const float*)d_in[4];
  const float* whh0b = (const float*)d_in[5];
  const float* b0b   = (const float*)d_in[6];
  const float* wih1f = (const float*)d_in[7];
  const float* whh1f = (const float*)d_in[8];
  const float* b1f   = (const float*)d_in[9];
  const float* wih1b = (const float*)d_in[10];
  const float* whh1b = (const float*)d_in[11];
  const float* b1b   = (const float*)d_in[12];
  const float* attw  = (const float*)d_in[13];
  const float* attb  = (const float*)d_in[14];
  const float* headw = (const float*)d_in[15];
  const float* headb = (const float*)d_in[16];
  float* out = (float*)d_out;

  char* p = (char*)d_ws;
  auto alloc = [&](size_t bytes) {
    char* r = p;
    p += (bytes + 511) & ~(size_t)511;
    return r;
  };
  ushort_t* xt    = (ushort_t*)alloc((size_t)32768 * 128 * 2);
  ushort_t* cwih0f = (ushort_t*)alloc(131072 * 2);
  ushort_t* cwih0b = (ushort_t*)alloc(131072 * 2);
  ushort_t* cwhh0f = (ushort_t*)alloc(262144 * 2);
  ushort_t* cwhh0b = (ushort_t*)alloc(262144 * 2);
  ushort_t* cwih1f = (ushort_t*)alloc(524288 * 2);
  ushort_t* cwih1b = (ushort_t*)alloc(524288 * 2);
  ushort_t* cwhh1f = (ushort_t*)alloc(262144 * 2);
  ushort_t* cwhh1b = (ushort_t*)alloc(262144 * 2);
  ushort_t* cwhead = (ushort_t*)alloc(65536 * 2);
  ushort_t* xpA = (ushort_t*)alloc((size_t)32768 * 1024 * 2);
  ushort_t* xpB = (ushort_t*)alloc((size_t)32768 * 1024 * 2);
  ushort_t* h0  = (ushort_t*)alloc((size_t)32768 * 512 * 2);
  ushort_t* h1  = (ushort_t*)alloc((size_t)32768 * 512 * 2);
  float* ebuf   = (float*)alloc(32 * 1024 * 4);
  ushort_t* ctx = xpA;  // reuse (xp dead by then)

  (void)in_sizes; (void)n_in; (void)out_size; (void)ws_size;

  // no sync state: batch-parallel recurrence needs no memset

  castw<<<512, 256, 0, stream>>>(wih0f, cwih0f, 131072);
  castw<<<512, 256, 0, stream>>>(wih0b, cwih0b, 131072);
  castw<<<1024, 256, 0, stream>>>(whh0f, cwhh0f, 262144);
  castw<<<1024, 256, 0, stream>>>(whh0b, cwhh0b, 262144);
  castw<<<2048, 256, 0, stream>>>(wih1f, cwih1f, 524288);
  castw<<<2048, 256, 0, stream>>>(wih1b, cwih1b, 524288);
  castw<<<1024, 256, 0, stream>>>(whh1f, cwhh1f, 262144);
  castw<<<1024, 256, 0, stream>>>(whh1b, cwhh1b, 262144);
  castw<<<256, 256, 0, stream>>>(headw, cwhead, 65536);
  castx<<<16384, 256, 0, stream>>>(x, xt);

  // layer 0: xp in transposed [t][g][b] layout (mode 2)
  gemm_bf16<<<dim3(8, 256), 256, 0, stream>>>(xt, cwih0f, b0f, xpA, 32768, 1024, 128, 2);
  gemm_bf16<<<dim3(8, 256), 256, 0, stream>>>(xt, cwih0b, b0b, xpB, 32768, 1024, 128, 2);
  lstm_layer<<<4, 512, 0, stream>>>(xpA, xpB, cwhh0f, cwhh0b, h0);

  // layer 1
  gemm_bf16<<<dim3(8, 256), 256, 0, stream>>>(h0, cwih1f, b1f, xpA, 32768, 1024, 512, 2);
  gemm_bf16<<<dim3(8, 256), 256, 0, stream>>>(h0, cwih1b, b1b, xpB, 32768, 1024, 512, 2);
  lstm_layer<<<4, 512, 0, stream>>>(xpA, xpB, cwhh1f, cwhh1b, h1);

  // attention + head
  attn_scores<<<32, 256, 0, stream>>>(h1, attw, attb, ebuf);
  attn_ctx<<<64, 256, 0, stream>>>(h1, ebuf, ctx);
  gemm_bf16<<<dim3(1, 256), 256, 0, stream>>>(ctx, cwhead, headb, out, 32768, 128, 512, 1);
}

// Round 10
// 10958.800 us; speedup vs baseline: 1.5859x; 1.0011x over previous
//
#include <hip/hip_runtime.h>

typedef unsigned short ushort_t;
typedef unsigned int uint_t;
typedef unsigned long long u64;
typedef __attribute__((ext_vector_type(8))) short short8;
typedef __attribute__((ext_vector_type(4))) float floatx4;

#define S_LEN 1024
#define BATCH 32
#define HDIM  256
#define GDIM  1024  /* 4H */
#define DIN   128

__device__ __forceinline__ float bf2f(ushort_t u) { return __uint_as_float(((unsigned)u) << 16); }
__device__ __forceinline__ float bf2fs(short s)   { return __uint_as_float(((unsigned)(unsigned short)s) << 16); }
__device__ __forceinline__ ushort_t f2bf(float f) {
  unsigned u = __float_as_uint(f);
  unsigned r = (u + 0x7fffu + ((u >> 16) & 1u)) >> 16;
  return (ushort_t)r;
}
__device__ __forceinline__ float sigf(float x) { return 1.f / (1.f + __expf(-x)); }
__device__ __forceinline__ float tanh_f(float x) {
  float ax = fabsf(x);
  float e = __expf(2.f * ax);
  float r = 1.f - 2.f / (e + 1.f);
  return x < 0.f ? -r : r;
}

__device__ __forceinline__ void load_lds16(const void* g, void* l) {
  __builtin_amdgcn_global_load_lds((const __attribute__((address_space(1))) unsigned int*)g,
                                   (__attribute__((address_space(3))) unsigned int*)l, 16, 0, 0);
}

// LDS-only barrier: drains lgkm (LDS ops) but NOT vmcnt, so in-flight global
// prefetches (ldxp, o-stream) and fire-and-forget stores (hout) stay in
// flight. sched_barrier fences prevent hipcc hoisting LDS ops across.
__device__ __forceinline__ void lds_barrier() {
  __builtin_amdgcn_sched_barrier(0);
  asm volatile("s_waitcnt lgkmcnt(0)" ::: "memory");
  __builtin_amdgcn_s_barrier();
  __builtin_amdgcn_sched_barrier(0);
}

// ---------------------------------------------------------------------------
// Generic bf16 MFMA GEMM: C[m][n] = sum_k A[m][k]*B[n][k] + bias[n]
// mode 0: bf16 at C[m*N+n]          (h layout [t][b][n], m = t*32+b)
// mode 1: fp32 at out[b][t][n]      (head output)
// mode 2: bf16 at C[t][n][b]        (xp transposed for vectorized recurrence)
// ---------------------------------------------------------------------------
__global__ __launch_bounds__(256) void gemm_bf16(
    const ushort_t* __restrict__ A, const ushort_t* __restrict__ Bw,
    const float* __restrict__ bias, void* __restrict__ Cout,
    int M, int N, int K, int mode)
{
  __shared__ __align__(16) ushort_t As[128 * 64];
  __shared__ __align__(16) ushort_t Bs[128 * 64];
  const int tid = threadIdx.x;
  const int lane = tid & 63, wid = tid >> 6;
  const int wm = wid >> 1, wn = wid & 1;
  const int bm = blockIdx.y, bn = blockIdx.x;
  const int l15 = lane & 15, q4 = lane >> 4;

  const int r  = tid >> 3;
  const int c8 = tid & 7;
  const int g8 = c8 ^ (r & 7);

  floatx4 zero4 = {0.f, 0.f, 0.f, 0.f};
  floatx4 acc[4][4];
#pragma unroll
  for (int mt = 0; mt < 4; ++mt)
#pragma unroll
    for (int nt = 0; nt < 4; ++nt) acc[mt][nt] = zero4;

  for (int k0 = 0; k0 < K; k0 += 64) {
    __syncthreads();
#pragma unroll
    for (int p = 0; p < 4; ++p) {
      int row = p * 32 + r;
      load_lds16(A + (size_t)(bm * 128 + row) * K + k0 + g8 * 8, (void*)(As + p * 2048 + wid * 512));
      load_lds16(Bw + (size_t)(bn * 128 + row) * K + k0 + g8 * 8, (void*)(Bs + p * 2048 + wid * 512));
    }
    __syncthreads();
#pragma unroll
    for (int ks = 0; ks < 2; ++ks) {
      const int kk = ks * 4 + q4;
      short8 af[4], bf[4];
#pragma unroll
      for (int mt = 0; mt < 4; ++mt) {
        int row = wm * 64 + mt * 16 + l15;
        af[mt] = *(const short8*)(As + row * 64 + ((kk ^ (row & 7)) << 3));
      }
#pragma unroll
      for (int nt = 0; nt < 4; ++nt) {
        int row = wn * 64 + nt * 16 + l15;
        bf[nt] = *(const short8*)(Bs + row * 64 + ((kk ^ (row & 7)) << 3));
      }
#pragma unroll
      for (int mt = 0; mt < 4; ++mt)
#pragma unroll
        for (int nt = 0; nt < 4; ++nt)
          acc[mt][nt] = __builtin_amdgcn_mfma_f32_16x16x32_bf16(af[mt], bf[nt], acc[mt][nt], 0, 0, 0);
    }
  }

#pragma unroll
  for (int mt = 0; mt < 4; ++mt)
#pragma unroll
    for (int nt = 0; nt < 4; ++nt)
#pragma unroll
      for (int rr = 0; rr < 4; ++rr) {
        int m = bm * 128 + wm * 64 + mt * 16 + q4 * 4 + rr;
        int n = bn * 128 + wn * 64 + nt * 16 + l15;
        float v = acc[mt][nt][rr] + bias[n];
        if (mode == 0) {
          ((ushort_t*)Cout)[(size_t)m * N + n] = f2bf(v);
        } else if (mode == 1) {
          int t = m >> 5, b = m & 31;
          ((float*)Cout)[(size_t)b * (S_LEN * DIN) + t * DIN + n] = v;
        } else {
          int t = m >> 5, b = m & 31;
          ((ushort_t*)Cout)[(size_t)t * (N * 32) + n * 32 + b] = f2bf(v);
        }
      }
}

// ---------------------------------------------------------------------------
// Bidirectional LSTM recurrence — batch-parallel (zero inter-WG comm), with
// 3-tier weight residency. MINIMAL-DIFF vs R9: __launch_bounds__(512, 2) ->
// (512, 1).
//
// R9 forensics: VGPR_Count=128 with ~240 needed; no scratch traffic (WRITE
// unchanged) but active-VALU 58% / active-MfmaUtil 17% -> the compiler
// DEMOTED the loop-invariant weight arrays to per-step L2 reloads. The 128
// cap matches CUDA minBlocksPerMultiprocessor semantics for the 2nd
// launch_bounds arg: (512,2) => 2 blocks x 8 waves = 4 waves/SIMD =>
// 512/4 = 128 regs. Every measured round fits that reading (R5:116<=128,
// R8 (1024,1):cap 128, m97 no-arg: 164>128). (512,1) => 2 waves/SIMD =>
// 256-reg cap under EITHER semantics; demand ~240 fits (weights can sit in
// AGPRs — unified file, MFMA reads A/B from AGPR).
//
// Everything else identical to R9:
//  * i,f gates (rows 0..511) in REGISTERS: 128 VGPRs.
//  * g gate (rows 512..767) in LDS [256][264] (132KB).
//  * o gate (rows 768..1023) streamed from L2 per step via 2x16-reg
//    half-buffers, half-2 pinned below half-1's MFMAs by sched_barrier(0).
//  * Grid = 4 WGs x 512 thr: dir = bx&1, bg = bx>>1 (16-batch group);
//    wave w owns h-cols w*32..+31 for ALL 4 gates -> i,f,g,o for a
//    (batch,col) land in the SAME lane -> register-local cell.
//  * One lgkm-only barrier per step; hout stores never drained in-loop.
// ---------------------------------------------------------------------------
__global__ __launch_bounds__(512, 1) void lstm_layer(
    const ushort_t* __restrict__ xpf, const ushort_t* __restrict__ xpb,
    const ushort_t* __restrict__ whhf, const ushort_t* __restrict__ whhb,
    ushort_t* __restrict__ hout)
{
  __shared__ __align__(16) ushort_t wg[256 * 264];     // g-gate weights, 132KB
  __shared__ __align__(16) ushort_t hbuf[2][16 * 264]; // h dbuf, 16.5KB

  const int bx = blockIdx.x;
  const int dir = bx & 1, bg = bx >> 1;

  const ushort_t* xp  = dir ? xpb : xpf;
  const ushort_t* whh = dir ? whhb : whhf;
  const int hoff = dir * 256;
  const int boff = bg * 16;

  const int tid = threadIdx.x, lane = tid & 63, w = tid >> 6;  // w in 0..7
  const int l15 = lane & 15, q4 = lane >> 4;

  // ---- prologue: g-gate -> LDS (padded stride 264) ----
  for (int idx = tid; idx < 256 * 32; idx += 512) {
    int row = idx >> 5, ch = idx & 31;
    *(short8*)(wg + row * 264 + ch * 8) =
        *(const short8*)(whh + (size_t)(512 + row) * 256 + ch * 8);
  }
  // zero hbuf[0]: h_{-1} = 0
  for (int i = tid; i < 16 * 132; i += 512) ((uint_t*)hbuf[0])[i] = 0u;

  // ---- permanent register fragments: i (rows 0..255), f (rows 256..511) ----
  short8 Bfi[2][8], Bff[2][8];
#pragma unroll
  for (int tl = 0; tl < 2; ++tl) {
    int rbase = w * 32 + tl * 16 + l15;
#pragma unroll
    for (int ks = 0; ks < 8; ++ks) {
      Bfi[tl][ks] = *(const short8*)(whh + (size_t)(rbase)       * 256 + ks * 32 + q4 * 8);
      Bff[tl][ks] = *(const short8*)(whh + (size_t)(256 + rbase) * 256 + ks * 32 + q4 * 8);
    }
  }

  // o-gate stream bases (rows 768..1023), per lane, per tile
  const ushort_t* ob0 = whh + (size_t)(768 + w * 32 + l15) * 256 + q4 * 8;
  const ushort_t* ob1 = ob0 + (size_t)16 * 256;

  float cst[2][4];
#pragma unroll
  for (int tl = 0; tl < 2; ++tl)
#pragma unroll
    for (int rr = 0; rr < 4; ++rr) cst[tl][rr] = 0.f;

  // xp: [t][g][b] layout; one u64 = 4 consecutive batches of this group
  u64 xr64[4][2];
  auto ldxp = [&](int tt) {
#pragma unroll
    for (int gg = 0; gg < 4; ++gg)
#pragma unroll
      for (int tl = 0; tl < 2; ++tl) {
        int g = gg * 256 + w * 32 + tl * 16 + l15;
        xr64[gg][tl] = *(const u64*)(xp + (size_t)tt * (GDIM * BATCH) + (size_t)g * 32 + boff + q4 * 4);
      }
  };

  ldxp((dir == 0) ? 0 : 1023);
  __syncthreads();  // prologue only: wg + hbuf[0] ready

  const int hr = tid >> 5;   // hout: local batch row 0..15
  const int hc = tid & 31;   // hout: 8-col group 0..31

  for (int sc = 0; sc < 1024; ++sc) {
    const int tcur  = (dir == 0) ? sc : 1023 - sc;
    const int tnext = (dir == 0) ? (sc < 1023 ? sc + 1 : 1023) : (sc < 1023 ? 1022 - sc : 0);
    const ushort_t* hb_c = hbuf[sc & 1];
    ushort_t* hb_n = hbuf[(sc + 1) & 1];

    // gates init = xp (counted vmcnt wait on xp loads issued last step)
    floatx4 acc[4][2];
#pragma unroll
    for (int gg = 0; gg < 4; ++gg)
#pragma unroll
      for (int tl = 0; tl < 2; ++tl) {
        u64 v = xr64[gg][tl];
#pragma unroll
        for (int rr = 0; rr < 4; ++rr)
          acc[gg][tl][rr] = bf2f((ushort_t)(v >> (16 * rr)));
      }

    // o-gate half-1 issue (BEFORE ldxp so its wait is vmcnt(8), not 0)
    short8 of[2][4];
#pragma unroll
    for (int k = 0; k < 4; ++k) {
      of[0][k] = *(const short8*)(ob0 + k * 32);
      of[1][k] = *(const short8*)(ob1 + k * 32);
    }

    ldxp(tnext);  // next step's xp; drains at o-half2 wait (~1500cy later)

    // ---- pass 1: i, f (regs) + g (LDS) ----
#pragma unroll
    for (int ks = 0; ks < 8; ++ks) {
      short8 a = *(const short8*)(hb_c + l15 * 264 + ks * 32 + q4 * 8);
      short8 g0 = *(const short8*)(wg + (w * 32 + l15) * 264 + ks * 32 + q4 * 8);
      short8 g1 = *(const short8*)(wg + (w * 32 + 16 + l15) * 264 + ks * 32 + q4 * 8);
      acc[0][0] = __builtin_amdgcn_mfma_f32_16x16x32_bf16(a, Bfi[0][ks], acc[0][0], 0, 0, 0);
      acc[0][1] = __builtin_amdgcn_mfma_f32_16x16x32_bf16(a, Bfi[1][ks], acc[0][1], 0, 0, 0);
      acc[1][0] = __builtin_amdgcn_mfma_f32_16x16x32_bf16(a, Bff[0][ks], acc[1][0], 0, 0, 0);
      acc[1][1] = __builtin_amdgcn_mfma_f32_16x16x32_bf16(a, Bff[1][ks], acc[1][1], 0, 0, 0);
      acc[2][0] = __builtin_amdgcn_mfma_f32_16x16x32_bf16(a, g0, acc[2][0], 0, 0, 0);
      acc[2][1] = __builtin_amdgcn_mfma_f32_16x16x32_bf16(a, g1, acc[2][1], 0, 0, 0);
    }

    // ---- o pass A (frags 0..3; waits o-half1, xp stays in flight) ----
#pragma unroll
    for (int ks = 0; ks < 4; ++ks) {
      short8 a = *(const short8*)(hb_c + l15 * 264 + ks * 32 + q4 * 8);
      acc[3][0] = __builtin_amdgcn_mfma_f32_16x16x32_bf16(a, of[0][ks], acc[3][0], 0, 0, 0);
      acc[3][1] = __builtin_amdgcn_mfma_f32_16x16x32_bf16(a, of[1][ks], acc[3][1], 0, 0, 0);
    }
    __builtin_amdgcn_sched_barrier(0);  // pin half-2 loads BELOW pass A (buffer reuse)
#pragma unroll
    for (int k = 0; k < 4; ++k) {
      of[0][k] = *(const short8*)(ob0 + (4 + k) * 32);
      of[1][k] = *(const short8*)(ob1 + (4 + k) * 32);
    }
#pragma unroll
    for (int ks = 4; ks < 8; ++ks) {
      short8 a = *(const short8*)(hb_c + l15 * 264 + ks * 32 + q4 * 8);
      acc[3][0] = __builtin_amdgcn_mfma_f32_16x16x32_bf16(a, of[0][ks - 4], acc[3][0], 0, 0, 0);
      acc[3][1] = __builtin_amdgcn_mfma_f32_16x16x32_bf16(a, of[1][ks - 4], acc[3][1], 0, 0, 0);
    }

    // ---- register-local LSTM cell: lane owns cols w*32+tl*16+l15,
    //      batches q4*4+rr; acc[0..3] = i,f,g,o (PyTorch order) ----
#pragma unroll
    for (int tl = 0; tl < 2; ++tl)
#pragma unroll
      for (int rr = 0; rr < 4; ++rr) {
        float c = sigf(acc[1][tl][rr]) * cst[tl][rr] + sigf(acc[0][tl][rr]) * tanh_f(acc[2][tl][rr]);
        cst[tl][rr] = c;
        float hv = sigf(acc[3][tl][rr]) * tanh_f(c);
        hb_n[(q4 * 4 + rr) * 264 + w * 32 + tl * 16 + l15] = f2bf(hv);
      }

    lds_barrier();  // h_t complete in hb_n; hout stores NOT drained here

    // hout: one coalesced 16B per thread (read-read with next step's MFMA
    // on hb_n; next step's cell writes go to hb_c — no race)
    short8 hv8 = *(const short8*)(hb_n + hr * 264 + hc * 8);
    *(short8*)(hout + (size_t)tcur * (BATCH * 512) + (size_t)(boff + hr) * 512 + hoff + hc * 8) = hv8;
  }
}

// ---------------------------------------------------------------------------
// Attention scores -> e = exp(s - max_t s), per batch b.
// ---------------------------------------------------------------------------
__global__ __launch_bounds__(256) void attn_scores(
    const ushort_t* __restrict__ h1, const float* __restrict__ attn_w,
    const float* __restrict__ attn_b, float* __restrict__ e_out)
{
  const int b = blockIdx.x;
  __shared__ float sbuf[1024];
  __shared__ float red[4];
  const int tid = threadIdx.x, lane = tid & 63, w = tid >> 6;

  float wreg[8];
#pragma unroll
  for (int i = 0; i < 8; ++i) wreg[i] = attn_w[lane * 8 + i];

  for (int t = w; t < 1024; t += 4) {
    short8 hv = *(const short8*)(h1 + (size_t)t * (BATCH * 512) + b * 512 + lane * 8);
    float dot = 0.f;
#pragma unroll
    for (int i = 0; i < 8; ++i) dot += bf2fs(hv[i]) * wreg[i];
#pragma unroll
    for (int off = 32; off; off >>= 1) dot += __shfl_xor(dot, off);
    if (lane == 0) sbuf[t] = dot + attn_b[0];
  }
  __syncthreads();
  float m = -1e30f;
  for (int t = tid; t < 1024; t += 256) m = fmaxf(m, sbuf[t]);
#pragma unroll
  for (int off = 32; off; off >>= 1) m = fmaxf(m, __shfl_xor(m, off));
  if (lane == 0) red[w] = m;
  __syncthreads();
  float mm = fmaxf(fmaxf(red[0], red[1]), fmaxf(red[2], red[3]));
  for (int t = tid; t < 1024; t += 256) e_out[b * 1024 + t] = __expf(sbuf[t] - mm);
}

// ---------------------------------------------------------------------------
// Cumulative context: ctx[t][b][c] = (sum_{u<=t} e_u h_u[c]) / (sum e_u), bf16.
// ---------------------------------------------------------------------------
__global__ __launch_bounds__(256) void attn_ctx(
    const ushort_t* __restrict__ h1, const float* __restrict__ e_in, ushort_t* __restrict__ ctx)
{
  const int b = blockIdx.x >> 1, half = blockIdx.x & 1;
  const int c = half * 256 + threadIdx.x;
  float num = 0.f, den = 0.f;
  const ushort_t* hp = h1 + b * 512 + c;
  ushort_t* cp = ctx + b * 512 + c;
  const float* ep = e_in + b * 1024;
#pragma unroll 4
  for (int t = 0; t < 1024; ++t) {
    float ev = ep[t];
    float hv = bf2f(hp[(size_t)t * (BATCH * 512)]);
    num += ev * hv;
    den += ev;
    cp[(size_t)t * (BATCH * 512)] = f2bf(num / den);
  }
}

// ---------------------------------------------------------------------------
// casts
// ---------------------------------------------------------------------------
__global__ void castw(const float* __restrict__ in, ushort_t* __restrict__ out, int n) {
  int i = blockIdx.x * 256 + threadIdx.x;
  if (i < n) out[i] = f2bf(in[i]);
}
__global__ void castx(const float* __restrict__ x, ushort_t* __restrict__ xt) {
  int i = blockIdx.x * 256 + threadIdx.x;  // over 32768*128
  int dcol = i & 127;
  int m = i >> 7;
  int b = m & 31, s = m >> 5;
  xt[i] = f2bf(x[(size_t)b * (S_LEN * DIN) + s * DIN + dcol]);
}

extern "C" void kernel_launch(void* const* d_in, const int* in_sizes, int n_in,
                              void* d_out, int out_size, void* d_ws, size_t ws_size,
                              hipStream_t stream)
{
  const float* x     = (const float*)d_in[0];
  const float* wih0f = (const float*)d_in[1];
  const float* whh0f = (const float*)d_in[2];
  const float* b0f   = (const float*)d_in[3];
  const float* wih0b = (const float*)d_in[4];
  const float* whh0b = (const float*)d_in[5];
  const float* b0b   = (const float*)d_in[6];
  const float* wih1f = (const float*)d_in[7];
  const float* whh1f = (const float*)d_in[8];
  const float* b1f   = (const float*)d_in[9];
  const float* wih1b = (const float*)d_in[10];
  const float* whh1b = (const float*)d_in[11];
  const float* b1b   = (const float*)d_in[12];
  const float* attw  = (const float*)d_in[13];
  const float* attb  = (const float*)d_in[14];
  const float* headw = (const float*)d_in[15];
  const float* headb = (const float*)d_in[16];
  float* out = (float*)d_out;

  char* p = (char*)d_ws;
  auto alloc = [&](size_t bytes) {
    char* r = p;
    p += (bytes + 511) & ~(size_t)511;
    return r;
  };
  ushort_t* xt    = (ushort_t*)alloc((size_t)32768 * 128 * 2);
  ushort_t* cwih0f = (ushort_t*)alloc(131072 * 2);
  ushort_t* cwih0b = (ushort_t*)alloc(131072 * 2);
  ushort_t* cwhh0f = (ushort_t*)alloc(262144 * 2);
  ushort_t* cwhh0b = (ushort_t*)alloc(262144 * 2);
  ushort_t* cwih1f = (ushort_t*)alloc(524288 * 2);
  ushort_t* cwih1b = (ushort_t*)alloc(524288 * 2);
  ushort_t* cwhh1f = (ushort_t*)alloc(262144 * 2);
  ushort_t* cwhh1b = (ushort_t*)alloc(262144 * 2);
  ushort_t* cwhead = (ushort_t*)alloc(65536 * 2);
  ushort_t* xpA = (ushort_t*)alloc((size_t)32768 * 1024 * 2);
  ushort_t* xpB = (ushort_t*)alloc((size_t)32768 * 1024 * 2);
  ushort_t* h0  = (ushort_t*)alloc((size_t)32768 * 512 * 2);
  ushort_t* h1  = (ushort_t*)alloc((size_t)32768 * 512 * 2);
  float* ebuf   = (float*)alloc(32 * 1024 * 4);
  ushort_t* ctx = xpA;  // reuse (xp dead by then)

  (void)in_sizes; (void)n_in; (void)out_size; (void)ws_size;

  // no sync state: batch-parallel recurrence needs no memset

  castw<<<512, 256, 0, stream>>>(wih0f, cwih0f, 131072);
  castw<<<512, 256, 0, stream>>>(wih0b, cwih0b, 131072);
  castw<<<1024, 256, 0, stream>>>(whh0f, cwhh0f, 262144);
  castw<<<1024, 256, 0, stream>>>(whh0b, cwhh0b, 262144);
  castw<<<2048, 256, 0, stream>>>(wih1f, cwih1f, 524288);
  castw<<<2048, 256, 0, stream>>>(wih1b, cwih1b, 524288);
  castw<<<1024, 256, 0, stream>>>(whh1f, cwhh1f, 262144);
  castw<<<1024, 256, 0, stream>>>(whh1b, cwhh1b, 262144);
  castw<<<256, 256, 0, stream>>>(headw, cwhead, 65536);
  castx<<<16384, 256, 0, stream>>>(x, xt);

  // layer 0: xp in transposed [t][g][b] layout (mode 2)
  gemm_bf16<<<dim3(8, 256), 256, 0, stream>>>(xt, cwih0f, b0f, xpA, 32768, 1024, 128, 2);
  gemm_bf16<<<dim3(8, 256), 256, 0, stream>>>(xt, cwih0b, b0b, xpB, 32768, 1024, 128, 2);
  lstm_layer<<<4, 512, 0, stream>>>(xpA, xpB, cwhh0f, cwhh0b, h0);

  // layer 1
  gemm_bf16<<<dim3(8, 256), 256, 0, stream>>>(h0, cwih1f, b1f, xpA, 32768, 1024, 512, 2);
  gemm_bf16<<<dim3(8, 256), 256, 0, stream>>>(h0, cwih1b, b1b, xpB, 32768, 1024, 512, 2);
  lstm_layer<<<4, 512, 0, stream>>>(xpA, xpB, cwhh1f, cwhh1b, h1);

  // attention + head
  attn_scores<<<32, 256, 0, stream>>>(h1, attw, attb, ebuf);
  attn_ctx<<<64, 256, 0, stream>>>(h1, ebuf, ctx);
  gemm_bf16<<<dim3(1, 256), 256, 0, stream>>>(ctx, cwhead, headb, out, 32768, 128, 512, 1);
}

// Round 11
// 10953.043 us; speedup vs baseline: 1.5867x; 1.0005x over previous
//
#include <hip/hip_runtime.h>

typedef unsigned short ushort_t;
typedef unsigned int uint_t;
typedef unsigned long long u64;
typedef __attribute__((ext_vector_type(8))) short short8;
typedef __attribute__((ext_vector_type(4))) float floatx4;

#define S_LEN 1024
#define BATCH 32
#define HDIM  256
#define GDIM  1024  /* 4H */
#define DIN   128

__device__ __forceinline__ float bf2f(ushort_t u) { return __uint_as_float(((unsigned)u) << 16); }
__device__ __forceinline__ float bf2fs(short s)   { return __uint_as_float(((unsigned)(unsigned short)s) << 16); }
__device__ __forceinline__ ushort_t f2bf(float f) {
  unsigned u = __float_as_uint(f);
  unsigned r = (u + 0x7fffu + ((u >> 16) & 1u)) >> 16;
  return (ushort_t)r;
}
__device__ __forceinline__ float sigf(float x) { return 1.f / (1.f + __expf(-x)); }
__device__ __forceinline__ float tanh_f(float x) {
  float ax = fabsf(x);
  float e = __expf(2.f * ax);
  float r = 1.f - 2.f / (e + 1.f);
  return x < 0.f ? -r : r;
}

__device__ __forceinline__ void load_lds16(const void* g, void* l) {
  __builtin_amdgcn_global_load_lds((const __attribute__((address_space(1))) unsigned int*)g,
                                   (__attribute__((address_space(3))) unsigned int*)l, 16, 0, 0);
}

// LDS-only barrier: drains lgkm (LDS ops) but NOT vmcnt, so in-flight global
// prefetches (ldxp, o-stream) and fire-and-forget stores (hout) stay in
// flight. sched_barrier fences prevent hipcc hoisting LDS ops across.
__device__ __forceinline__ void lds_barrier() {
  __builtin_amdgcn_sched_barrier(0);
  asm volatile("s_waitcnt lgkmcnt(0)" ::: "memory");
  __builtin_amdgcn_s_barrier();
  __builtin_amdgcn_sched_barrier(0);
}

// ---------------------------------------------------------------------------
// Generic bf16 MFMA GEMM: C[m][n] = sum_k A[m][k]*B[n][k] + bias[n]
// mode 0: bf16 at C[m*N+n]          (h layout [t][b][n], m = t*32+b)
// mode 1: fp32 at out[b][t][n]      (head output)
// mode 2: bf16 at C[t][n][b]        (xp transposed for vectorized recurrence)
// ---------------------------------------------------------------------------
__global__ __launch_bounds__(256) void gemm_bf16(
    const ushort_t* __restrict__ A, const ushort_t* __restrict__ Bw,
    const float* __restrict__ bias, void* __restrict__ Cout,
    int M, int N, int K, int mode)
{
  __shared__ __align__(16) ushort_t As[128 * 64];
  __shared__ __align__(16) ushort_t Bs[128 * 64];
  const int tid = threadIdx.x;
  const int lane = tid & 63, wid = tid >> 6;
  const int wm = wid >> 1, wn = wid & 1;
  const int bm = blockIdx.y, bn = blockIdx.x;
  const int l15 = lane & 15, q4 = lane >> 4;

  const int r  = tid >> 3;
  const int c8 = tid & 7;
  const int g8 = c8 ^ (r & 7);

  floatx4 zero4 = {0.f, 0.f, 0.f, 0.f};
  floatx4 acc[4][4];
#pragma unroll
  for (int mt = 0; mt < 4; ++mt)
#pragma unroll
    for (int nt = 0; nt < 4; ++nt) acc[mt][nt] = zero4;

  for (int k0 = 0; k0 < K; k0 += 64) {
    __syncthreads();
#pragma unroll
    for (int p = 0; p < 4; ++p) {
      int row = p * 32 + r;
      load_lds16(A + (size_t)(bm * 128 + row) * K + k0 + g8 * 8, (void*)(As + p * 2048 + wid * 512));
      load_lds16(Bw + (size_t)(bn * 128 + row) * K + k0 + g8 * 8, (void*)(Bs + p * 2048 + wid * 512));
    }
    __syncthreads();
#pragma unroll
    for (int ks = 0; ks < 2; ++ks) {
      const int kk = ks * 4 + q4;
      short8 af[4], bf[4];
#pragma unroll
      for (int mt = 0; mt < 4; ++mt) {
        int row = wm * 64 + mt * 16 + l15;
        af[mt] = *(const short8*)(As + row * 64 + ((kk ^ (row & 7)) << 3));
      }
#pragma unroll
      for (int nt = 0; nt < 4; ++nt) {
        int row = wn * 64 + nt * 16 + l15;
        bf[nt] = *(const short8*)(Bs + row * 64 + ((kk ^ (row & 7)) << 3));
      }
#pragma unroll
      for (int mt = 0; mt < 4; ++mt)
#pragma unroll
        for (int nt = 0; nt < 4; ++nt)
          acc[mt][nt] = __builtin_amdgcn_mfma_f32_16x16x32_bf16(af[mt], bf[nt], acc[mt][nt], 0, 0, 0);
    }
  }

#pragma unroll
  for (int mt = 0; mt < 4; ++mt)
#pragma unroll
    for (int nt = 0; nt < 4; ++nt)
#pragma unroll
      for (int rr = 0; rr < 4; ++rr) {
        int m = bm * 128 + wm * 64 + mt * 16 + q4 * 4 + rr;
        int n = bn * 128 + wn * 64 + nt * 16 + l15;
        float v = acc[mt][nt][rr] + bias[n];
        if (mode == 0) {
          ((ushort_t*)Cout)[(size_t)m * N + n] = f2bf(v);
        } else if (mode == 1) {
          int t = m >> 5, b = m & 31;
          ((float*)Cout)[(size_t)b * (S_LEN * DIN) + t * DIN + n] = v;
        } else {
          int t = m >> 5, b = m & 31;
          ((ushort_t*)Cout)[(size_t)t * (N * 32) + n * 32 + b] = f2bf(v);
        }
      }
}

// ---------------------------------------------------------------------------
// Bidirectional LSTM recurrence — batch-parallel (zero inter-WG comm), with
// 3-tier weight residency. MINIMAL-DIFF vs R10: replace __launch_bounds__
// with explicit amdgpu attributes:
//   amdgpu_flat_work_group_size(512,512) + amdgpu_waves_per_eu(1,2)
//
// R9/R10 forensics: VGPR_Count pinned at exactly 128 under BOTH (512,2) and
// (512,1) — so __launch_bounds__ does not lower the compiler's internal
// waves-per-eu target (default 4/EU -> 128-reg budget), and the ~240-reg
// weight working set gets demoted to per-step L2 reloads (12.3kcy/step,
// active-MfmaUtil 17%, no scratch traffic). amdgpu_waves_per_eu(1,2) sets
// the attribute the register-budget computation actually reads: min=1 ->
// full-file budget; max=2 is truthful (148.5KB LDS caps us at 1 WG/CU =
// 2 waves/EU anyway). Kernel body is byte-identical to R10 for clean A/B.
//
// Decision table: VGPR >= ~200 & dur ~1.5-2.5ms -> residency achieved;
// VGPR = 128 & dur ~5.1ms -> allocator path conclusively dead, revert to R6
// (best verified: 3422us/layer).
//
//  * i,f gates (rows 0..511) in REGISTERS: 128 VGPRs.
//  * g gate (rows 512..767) in LDS [256][264] (132KB).
//  * o gate (rows 768..1023) streamed from L2 per step via 2x16-reg
//    half-buffers, half-2 pinned below half-1's MFMAs by sched_barrier(0).
//  * Grid = 4 WGs x 512 thr: dir = bx&1, bg = bx>>1 (16-batch group);
//    wave w owns h-cols w*32..+31 for ALL 4 gates -> i,f,g,o for a
//    (batch,col) land in the SAME lane -> register-local cell.
//  * One lgkm-only barrier per step; hout stores never drained in-loop.
// ---------------------------------------------------------------------------
__global__ void
__attribute__((amdgpu_flat_work_group_size(512, 512), amdgpu_waves_per_eu(1, 2)))
lstm_layer(
    const ushort_t* __restrict__ xpf, const ushort_t* __restrict__ xpb,
    const ushort_t* __restrict__ whhf, const ushort_t* __restrict__ whhb,
    ushort_t* __restrict__ hout)
{
  __shared__ __align__(16) ushort_t wg[256 * 264];     // g-gate weights, 132KB
  __shared__ __align__(16) ushort_t hbuf[2][16 * 264]; // h dbuf, 16.5KB

  const int bx = blockIdx.x;
  const int dir = bx & 1, bg = bx >> 1;

  const ushort_t* xp  = dir ? xpb : xpf;
  const ushort_t* whh = dir ? whhb : whhf;
  const int hoff = dir * 256;
  const int boff = bg * 16;

  const int tid = threadIdx.x, lane = tid & 63, w = tid >> 6;  // w in 0..7
  const int l15 = lane & 15, q4 = lane >> 4;

  // ---- prologue: g-gate -> LDS (padded stride 264) ----
  for (int idx = tid; idx < 256 * 32; idx += 512) {
    int row = idx >> 5, ch = idx & 31;
    *(short8*)(wg + row * 264 + ch * 8) =
        *(const short8*)(whh + (size_t)(512 + row) * 256 + ch * 8);
  }
  // zero hbuf[0]: h_{-1} = 0
  for (int i = tid; i < 16 * 132; i += 512) ((uint_t*)hbuf[0])[i] = 0u;

  // ---- permanent register fragments: i (rows 0..255), f (rows 256..511) ----
  short8 Bfi[2][8], Bff[2][8];
#pragma unroll
  for (int tl = 0; tl < 2; ++tl) {
    int rbase = w * 32 + tl * 16 + l15;
#pragma unroll
    for (int ks = 0; ks < 8; ++ks) {
      Bfi[tl][ks] = *(const short8*)(whh + (size_t)(rbase)       * 256 + ks * 32 + q4 * 8);
      Bff[tl][ks] = *(const short8*)(whh + (size_t)(256 + rbase) * 256 + ks * 32 + q4 * 8);
    }
  }

  // o-gate stream bases (rows 768..1023), per lane, per tile
  const ushort_t* ob0 = whh + (size_t)(768 + w * 32 + l15) * 256 + q4 * 8;
  const ushort_t* ob1 = ob0 + (size_t)16 * 256;

  float cst[2][4];
#pragma unroll
  for (int tl = 0; tl < 2; ++tl)
#pragma unroll
    for (int rr = 0; rr < 4; ++rr) cst[tl][rr] = 0.f;

  // xp: [t][g][b] layout; one u64 = 4 consecutive batches of this group
  u64 xr64[4][2];
  auto ldxp = [&](int tt) {
#pragma unroll
    for (int gg = 0; gg < 4; ++gg)
#pragma unroll
      for (int tl = 0; tl < 2; ++tl) {
        int g = gg * 256 + w * 32 + tl * 16 + l15;
        xr64[gg][tl] = *(const u64*)(xp + (size_t)tt * (GDIM * BATCH) + (size_t)g * 32 + boff + q4 * 4);
      }
  };

  ldxp((dir == 0) ? 0 : 1023);
  __syncthreads();  // prologue only: wg + hbuf[0] ready

  const int hr = tid >> 5;   // hout: local batch row 0..15
  const int hc = tid & 31;   // hout: 8-col group 0..31

  for (int sc = 0; sc < 1024; ++sc) {
    const int tcur  = (dir == 0) ? sc : 1023 - sc;
    const int tnext = (dir == 0) ? (sc < 1023 ? sc + 1 : 1023) : (sc < 1023 ? 1022 - sc : 0);
    const ushort_t* hb_c = hbuf[sc & 1];
    ushort_t* hb_n = hbuf[(sc + 1) & 1];

    // gates init = xp (counted vmcnt wait on xp loads issued last step)
    floatx4 acc[4][2];
#pragma unroll
    for (int gg = 0; gg < 4; ++gg)
#pragma unroll
      for (int tl = 0; tl < 2; ++tl) {
        u64 v = xr64[gg][tl];
#pragma unroll
        for (int rr = 0; rr < 4; ++rr)
          acc[gg][tl][rr] = bf2f((ushort_t)(v >> (16 * rr)));
      }

    // o-gate half-1 issue (BEFORE ldxp so its wait is vmcnt(8), not 0)
    short8 of[2][4];
#pragma unroll
    for (int k = 0; k < 4; ++k) {
      of[0][k] = *(const short8*)(ob0 + k * 32);
      of[1][k] = *(const short8*)(ob1 + k * 32);
    }

    ldxp(tnext);  // next step's xp; drains at o-half2 wait (~1500cy later)

    // ---- pass 1: i, f (regs) + g (LDS) ----
#pragma unroll
    for (int ks = 0; ks < 8; ++ks) {
      short8 a = *(const short8*)(hb_c + l15 * 264 + ks * 32 + q4 * 8);
      short8 g0 = *(const short8*)(wg + (w * 32 + l15) * 264 + ks * 32 + q4 * 8);
      short8 g1 = *(const short8*)(wg + (w * 32 + 16 + l15) * 264 + ks * 32 + q4 * 8);
      acc[0][0] = __builtin_amdgcn_mfma_f32_16x16x32_bf16(a, Bfi[0][ks], acc[0][0], 0, 0, 0);
      acc[0][1] = __builtin_amdgcn_mfma_f32_16x16x32_bf16(a, Bfi[1][ks], acc[0][1], 0, 0, 0);
      acc[1][0] = __builtin_amdgcn_mfma_f32_16x16x32_bf16(a, Bff[0][ks], acc[1][0], 0, 0, 0);
      acc[1][1] = __builtin_amdgcn_mfma_f32_16x16x32_bf16(a, Bff[1][ks], acc[1][1], 0, 0, 0);
      acc[2][0] = __builtin_amdgcn_mfma_f32_16x16x32_bf16(a, g0, acc[2][0], 0, 0, 0);
      acc[2][1] = __builtin_amdgcn_mfma_f32_16x16x32_bf16(a, g1, acc[2][1], 0, 0, 0);
    }

    // ---- o pass A (frags 0..3; waits o-half1, xp stays in flight) ----
#pragma unroll
    for (int ks = 0; ks < 4; ++ks) {
      short8 a = *(const short8*)(hb_c + l15 * 264 + ks * 32 + q4 * 8);
      acc[3][0] = __builtin_amdgcn_mfma_f32_16x16x32_bf16(a, of[0][ks], acc[3][0], 0, 0, 0);
      acc[3][1] = __builtin_amdgcn_mfma_f32_16x16x32_bf16(a, of[1][ks], acc[3][1], 0, 0, 0);
    }
    __builtin_amdgcn_sched_barrier(0);  // pin half-2 loads BELOW pass A (buffer reuse)
#pragma unroll
    for (int k = 0; k < 4; ++k) {
      of[0][k] = *(const short8*)(ob0 + (4 + k) * 32);
      of[1][k] = *(const short8*)(ob1 + (4 + k) * 32);
    }
#pragma unroll
    for (int ks = 4; ks < 8; ++ks) {
      short8 a = *(const short8*)(hb_c + l15 * 264 + ks * 32 + q4 * 8);
      acc[3][0] = __builtin_amdgcn_mfma_f32_16x16x32_bf16(a, of[0][ks - 4], acc[3][0], 0, 0, 0);
      acc[3][1] = __builtin_amdgcn_mfma_f32_16x16x32_bf16(a, of[1][ks - 4], acc[3][1], 0, 0, 0);
    }

    // ---- register-local LSTM cell: lane owns cols w*32+tl*16+l15,
    //      batches q4*4+rr; acc[0..3] = i,f,g,o (PyTorch order) ----
#pragma unroll
    for (int tl = 0; tl < 2; ++tl)
#pragma unroll
      for (int rr = 0; rr < 4; ++rr) {
        float c = sigf(acc[1][tl][rr]) * cst[tl][rr] + sigf(acc[0][tl][rr]) * tanh_f(acc[2][tl][rr]);
        cst[tl][rr] = c;
        float hv = sigf(acc[3][tl][rr]) * tanh_f(c);
        hb_n[(q4 * 4 + rr) * 264 + w * 32 + tl * 16 + l15] = f2bf(hv);
      }

    lds_barrier();  // h_t complete in hb_n; hout stores NOT drained here

    // hout: one coalesced 16B per thread (read-read with next step's MFMA
    // on hb_n; next step's cell writes go to hb_c — no race)
    short8 hv8 = *(const short8*)(hb_n + hr * 264 + hc * 8);
    *(short8*)(hout + (size_t)tcur * (BATCH * 512) + (size_t)(boff + hr) * 512 + hoff + hc * 8) = hv8;
  }
}

// ---------------------------------------------------------------------------
// Attention scores -> e = exp(s - max_t s), per batch b.
// ---------------------------------------------------------------------------
__global__ __launch_bounds__(256) void attn_scores(
    const ushort_t* __restrict__ h1, const float* __restrict__ attn_w,
    const float* __restrict__ attn_b, float* __restrict__ e_out)
{
  const int b = blockIdx.x;
  __shared__ float sbuf[1024];
  __shared__ float red[4];
  const int tid = threadIdx.x, lane = tid & 63, w = tid >> 6;

  float wreg[8];
#pragma unroll
  for (int i = 0; i < 8; ++i) wreg[i] = attn_w[lane * 8 + i];

  for (int t = w; t < 1024; t += 4) {
    short8 hv = *(const short8*)(h1 + (size_t)t * (BATCH * 512) + b * 512 + lane * 8);
    float dot = 0.f;
#pragma unroll
    for (int i = 0; i < 8; ++i) dot += bf2fs(hv[i]) * wreg[i];
#pragma unroll
    for (int off = 32; off; off >>= 1) dot += __shfl_xor(dot, off);
    if (lane == 0) sbuf[t] = dot + attn_b[0];
  }
  __syncthreads();
  float m = -1e30f;
  for (int t = tid; t < 1024; t += 256) m = fmaxf(m, sbuf[t]);
#pragma unroll
  for (int off = 32; off; off >>= 1) m = fmaxf(m, __shfl_xor(m, off));
  if (lane == 0) red[w] = m;
  __syncthreads();
  float mm = fmaxf(fmaxf(red[0], red[1]), fmaxf(red[2], red[3]));
  for (int t = tid; t < 1024; t += 256) e_out[b * 1024 + t] = __expf(sbuf[t] - mm);
}

// ---------------------------------------------------------------------------
// Cumulative context: ctx[t][b][c] = (sum_{u<=t} e_u h_u[c]) / (sum e_u), bf16.
// ---------------------------------------------------------------------------
__global__ __launch_bounds__(256) void attn_ctx(
    const ushort_t* __restrict__ h1, const float* __restrict__ e_in, ushort_t* __restrict__ ctx)
{
  const int b = blockIdx.x >> 1, half = blockIdx.x & 1;
  const int c = half * 256 + threadIdx.x;
  float num = 0.f, den = 0.f;
  const ushort_t* hp = h1 + b * 512 + c;
  ushort_t* cp = ctx + b * 512 + c;
  const float* ep = e_in + b * 1024;
#pragma unroll 4
  for (int t = 0; t < 1024; ++t) {
    float ev = ep[t];
    float hv = bf2f(hp[(size_t)t * (BATCH * 512)]);
    num += ev * hv;
    den += ev;
    cp[(size_t)t * (BATCH * 512)] = f2bf(num / den);
  }
}

// ---------------------------------------------------------------------------
// casts
// ---------------------------------------------------------------------------
__global__ void castw(const float* __restrict__ in, ushort_t* __restrict__ out, int n) {
  int i = blockIdx.x * 256 + threadIdx.x;
  if (i < n) out[i] = f2bf(in[i]);
}
__global__ void castx(const float* __restrict__ x, ushort_t* __restrict__ xt) {
  int i = blockIdx.x * 256 + threadIdx.x;  // over 32768*128
  int dcol = i & 127;
  int m = i >> 7;
  int b = m & 31, s = m >> 5;
  xt[i] = f2bf(x[(size_t)b * (S_LEN * DIN) + s * DIN + dcol]);
}

extern "C" void kernel_launch(void* const* d_in, const int* in_sizes, int n_in,
                              void* d_out, int out_size, void* d_ws, size_t ws_size,
                              hipStream_t stream)
{
  const float* x     = (const float*)d_in[0];
  const float* wih0f = (const float*)d_in[1];
  const float* whh0f = (const float*)d_in[2];
  const float* b0f   = (const float*)d_in[3];
  const float* wih0b = (const float*)d_in[4];
  const float* whh0b = (const float*)d_in[5];
  const float* b0b   = (const float*)d_in[6];
  const float* wih1f = (const float*)d_in[7];
  const float* whh1f = (const float*)d_in[8];
  const float* b1f   = (const float*)d_in[9];
  const float* wih1b = (const float*)d_in[10];
  const float* whh1b = (const float*)d_in[11];
  const float* b1b   = (const float*)d_in[12];
  const float* attw  = (const float*)d_in[13];
  const float* attb  = (const float*)d_in[14];
  const float* headw = (const float*)d_in[15];
  const float* headb = (const float*)d_in[16];
  float* out = (float*)d_out;

  char* p = (char*)d_ws;
  auto alloc = [&](size_t bytes) {
    char* r = p;
    p += (bytes + 511) & ~(size_t)511;
    return r;
  };
  ushort_t* xt    = (ushort_t*)alloc((size_t)32768 * 128 * 2);
  ushort_t* cwih0f = (ushort_t*)alloc(131072 * 2);
  ushort_t* cwih0b = (ushort_t*)alloc(131072 * 2);
  ushort_t* cwhh0f = (ushort_t*)alloc(262144 * 2);
  ushort_t* cwhh0b = (ushort_t*)alloc(262144 * 2);
  ushort_t* cwih1f = (ushort_t*)alloc(524288 * 2);
  ushort_t* cwih1b = (ushort_t*)alloc(524288 * 2);
  ushort_t* cwhh1f = (ushort_t*)alloc(262144 * 2);
  ushort_t* cwhh1b = (ushort_t*)alloc(262144 * 2);
  ushort_t* cwhead = (ushort_t*)alloc(65536 * 2);
  ushort_t* xpA = (ushort_t*)alloc((size_t)32768 * 1024 * 2);
  ushort_t* xpB = (ushort_t*)alloc((size_t)32768 * 1024 * 2);
  ushort_t* h0  = (ushort_t*)alloc((size_t)32768 * 512 * 2);
  ushort_t* h1  = (ushort_t*)alloc((size_t)32768 * 512 * 2);
  float* ebuf   = (float*)alloc(32 * 1024 * 4);
  ushort_t* ctx = xpA;  // reuse (xp dead by then)

  (void)in_sizes; (void)n_in; (void)out_size; (void)ws_size;

  // no sync state: batch-parallel recurrence needs no memset

  castw<<<512, 256, 0, stream>>>(wih0f, cwih0f, 131072);
  castw<<<512, 256, 0, stream>>>(wih0b, cwih0b, 131072);
  castw<<<1024, 256, 0, stream>>>(whh0f, cwhh0f, 262144);
  castw<<<1024, 256, 0, stream>>>(whh0b, cwhh0b, 262144);
  castw<<<2048, 256, 0, stream>>>(wih1f, cwih1f, 524288);
  castw<<<2048, 256, 0, stream>>>(wih1b, cwih1b, 524288);
  castw<<<1024, 256, 0, stream>>>(whh1f, cwhh1f, 262144);
  castw<<<1024, 256, 0, stream>>>(whh1b, cwhh1b, 262144);
  castw<<<256, 256, 0, stream>>>(headw, cwhead, 65536);
  castx<<<16384, 256, 0, stream>>>(x, xt);

  // layer 0: xp in transposed [t][g][b] layout (mode 2)
  gemm_bf16<<<dim3(8, 256), 256, 0, stream>>>(xt, cwih0f, b0f, xpA, 32768, 1024, 128, 2);
  gemm_bf16<<<dim3(8, 256), 256, 0, stream>>>(xt, cwih0b, b0b, xpB, 32768, 1024, 128, 2);
  lstm_layer<<<4, 512, 0, stream>>>(xpA, xpB, cwhh0f, cwhh0b, h0);

  // layer 1
  gemm_bf16<<<dim3(8, 256), 256, 0, stream>>>(h0, cwih1f, b1f, xpA, 32768, 1024, 512, 2);
  gemm_bf16<<<dim3(8, 256), 256, 0, stream>>>(h0, cwih1b, b1b, xpB, 32768, 1024, 512, 2);
  lstm_layer<<<4, 512, 0, stream>>>(xpA, xpB, cwhh1f, cwhh1b, h1);

  // attention + head
  attn_scores<<<32, 256, 0, stream>>>(h1, attw, attb, ebuf);
  attn_ctx<<<64, 256, 0, stream>>>(h1, ebuf, ctx);
  gemm_bf16<<<dim3(1, 256), 256, 0, stream>>>(ctx, cwhead, headb, out, 32768, 128, 512, 1);
}

// Round 12
// 7542.360 us; speedup vs baseline: 2.3043x; 1.4522x over previous
//
#include <hip/hip_runtime.h>

typedef unsigned short ushort_t;
typedef unsigned int uint_t;
typedef unsigned long long u64;
typedef __attribute__((ext_vector_type(8))) short short8;
typedef __attribute__((ext_vector_type(4))) float floatx4;

#define S_LEN 1024
#define BATCH 32
#define HDIM  256
#define GDIM  1024  /* 4H */
#define DIN   128

__device__ __forceinline__ float bf2f(ushort_t u) { return __uint_as_float(((unsigned)u) << 16); }
__device__ __forceinline__ float bf2fs(short s)   { return __uint_as_float(((unsigned)(unsigned short)s) << 16); }
__device__ __forceinline__ ushort_t f2bf(float f) {
  unsigned u = __float_as_uint(f);
  unsigned r = (u + 0x7fffu + ((u >> 16) & 1u)) >> 16;
  return (ushort_t)r;
}
__device__ __forceinline__ float sigf(float x) { return 1.f / (1.f + __expf(-x)); }
__device__ __forceinline__ float tanh_f(float x) {
  float ax = fabsf(x);
  float e = __expf(2.f * ax);
  float r = 1.f - 2.f / (e + 1.f);
  return x < 0.f ? -r : r;
}

__device__ __forceinline__ void load_lds16(const void* g, void* l) {
  __builtin_amdgcn_global_load_lds((const __attribute__((address_space(1))) unsigned int*)g,
                                   (__attribute__((address_space(3))) unsigned int*)l, 16, 0, 0);
}
__device__ __forceinline__ void vm0() { asm volatile("s_waitcnt vmcnt(0)" ::: "memory"); }

// LDS-only barrier: drains lgkm (LDS ops) but NOT vmcnt, so in-flight global
// prefetches and store-acks are NOT serialized here. sched_barrier fences
// prevent hipcc from hoisting LDS ops across (rule #18).
__device__ __forceinline__ void lds_barrier() {
  __builtin_amdgcn_sched_barrier(0);
  asm volatile("s_waitcnt lgkmcnt(0)" ::: "memory");
  __builtin_amdgcn_s_barrier();
  __builtin_amdgcn_sched_barrier(0);
}

// ---------------------------------------------------------------------------
// Generic bf16 MFMA GEMM: C[m][n] = sum_k A[m][k]*B[n][k] + bias[n]
// mode 0: bf16 at C[m*N+n]          (h layout [t][b][n], m = t*32+b)
// mode 1: fp32 at out[b][t][n]      (head output)
// mode 2: bf16 at C[t][n][b]        (xp transposed for vectorized recurrence)
// ---------------------------------------------------------------------------
__global__ __launch_bounds__(256) void gemm_bf16(
    const ushort_t* __restrict__ A, const ushort_t* __restrict__ Bw,
    const float* __restrict__ bias, void* __restrict__ Cout,
    int M, int N, int K, int mode)
{
  __shared__ __align__(16) ushort_t As[128 * 64];
  __shared__ __align__(16) ushort_t Bs[128 * 64];
  const int tid = threadIdx.x;
  const int lane = tid & 63, wid = tid >> 6;
  const int wm = wid >> 1, wn = wid & 1;
  const int bm = blockIdx.y, bn = blockIdx.x;
  const int l15 = lane & 15, q4 = lane >> 4;

  const int r  = tid >> 3;
  const int c8 = tid & 7;
  const int g8 = c8 ^ (r & 7);

  floatx4 zero4 = {0.f, 0.f, 0.f, 0.f};
  floatx4 acc[4][4];
#pragma unroll
  for (int mt = 0; mt < 4; ++mt)
#pragma unroll
    for (int nt = 0; nt < 4; ++nt) acc[mt][nt] = zero4;

  for (int k0 = 0; k0 < K; k0 += 64) {
    __syncthreads();
#pragma unroll
    for (int p = 0; p < 4; ++p) {
      int row = p * 32 + r;
      load_lds16(A + (size_t)(bm * 128 + row) * K + k0 + g8 * 8, (void*)(As + p * 2048 + wid * 512));
      load_lds16(Bw + (size_t)(bn * 128 + row) * K + k0 + g8 * 8, (void*)(Bs + p * 2048 + wid * 512));
    }
    __syncthreads();
#pragma unroll
    for (int ks = 0; ks < 2; ++ks) {
      const int kk = ks * 4 + q4;
      short8 af[4], bf[4];
#pragma unroll
      for (int mt = 0; mt < 4; ++mt) {
        int row = wm * 64 + mt * 16 + l15;
        af[mt] = *(const short8*)(As + row * 64 + ((kk ^ (row & 7)) << 3));
      }
#pragma unroll
      for (int nt = 0; nt < 4; ++nt) {
        int row = wn * 64 + nt * 16 + l15;
        bf[nt] = *(const short8*)(Bs + row * 64 + ((kk ^ (row & 7)) << 3));
      }
#pragma unroll
      for (int mt = 0; mt < 4; ++mt)
#pragma unroll
        for (int nt = 0; nt < 4; ++nt)
          acc[mt][nt] = __builtin_amdgcn_mfma_f32_16x16x32_bf16(af[mt], bf[nt], acc[mt][nt], 0, 0, 0);
    }
  }

#pragma unroll
  for (int mt = 0; mt < 4; ++mt)
#pragma unroll
    for (int nt = 0; nt < 4; ++nt)
#pragma unroll
      for (int rr = 0; rr < 4; ++rr) {
        int m = bm * 128 + wm * 64 + mt * 16 + q4 * 4 + rr;
        int n = bn * 128 + wn * 64 + nt * 16 + l15;
        float v = acc[mt][nt][rr] + bias[n];
        if (mode == 0) {
          ((ushort_t*)Cout)[(size_t)m * N + n] = f2bf(v);
        } else if (mode == 1) {
          int t = m >> 5, b = m & 31;
          ((float*)Cout)[(size_t)b * (S_LEN * DIN) + t * DIN + n] = v;
        } else {
          int t = m >> 5, b = m & 31;
          ((ushort_t*)Cout)[(size_t)t * (N * 32) + n * 32 + b] = f2bf(v);
        }
      }
}

// ---------------------------------------------------------------------------
// Bidirectional LSTM recurrence — R6⊕R7 HYBRID on the proven R4 topology
// (16 WGs: dir = bx&1, j = bx>>1; untagged 64B/thread exchange, epoch-gated).
//
// R6 proved the FUSED consume (spec-load data+epoch together, accept on
// epoch>=sc: 1 MALL RT instead of poll-then-load's 2) but wasted the gain by
// putting ldxp+unpack inside the publish path before the epoch. R7 proved
// the CLEAN publish (stores -> one vm0 -> barrier -> epoch, ldxp hidden) but
// kept the 2-RT consume. This round combines both fixes:
//
//  per step:
//   1. fused consume spin (queue CLEAN — drained at prev publish vm0, so the
//      spin's implicit per-iteration vmcnt(0) costs nothing extra)
//   2. unpack xp[sc] (issued last step inside the vm0 window; complete; free)
//   3. lds_barrier -> MFMA -> stage -> lds_barrier -> cell
//   4. publish: comm + hbuf own-slice + hout stores -> ldxp(tnext) -> ONE
//      vm0 (comm/hout acks overlap the xp RT) -> raw barrier -> epoch.
//      ldxp INSIDE the vm0 window => next spin never drains a fresh load
//      (R4's trap); epoch never delayed by an unpack (R6's trap).
//
// Freshness on the accept iteration: producer's vm0 guarantees data@MALL
// >= 1 full RT before the epoch store even issues; consumer's data+epoch
// loads are serviced ~together. R6 measured this exposure at absmax 0.00305
// (PASSED). Overwrite safety (2-parity double buffer, same induction):
// observing B's epoch sc+1 implies B's step-sc consume loads completed
// (their values fed the accept condition and the MFMA, all before B's
// program-ordered publish+vm0+epoch). Graph-replay safe: epochs zeroed per
// launch; comm data is epoch-gated so it needs no init.
// ---------------------------------------------------------------------------
__global__ __launch_bounds__(256) void lstm_layer(
    const ushort_t* __restrict__ xpf, const ushort_t* __restrict__ xpb,
    const ushort_t* __restrict__ whhf, const ushort_t* __restrict__ whhb,
    ushort_t* __restrict__ hout, u64* __restrict__ comm, u64* __restrict__ epochs)
{
  const int bx = blockIdx.x;
  const int dir = bx & 1, j = bx >> 1;

  const ushort_t* xp  = dir ? xpb : xpf;
  const ushort_t* whh = dir ? whhb : whhf;
  u64* commd = comm + (size_t)dir * 4096;  // 2 parities x 2048 u64
  const int hoff = dir * 256;

  __shared__ __align__(16) ushort_t hbuf[32 * 264];  // h_{t-1} bf16, stride 264
  __shared__ __align__(16) float stage[32 * 133];    // gates fp32, stride 133

  const int tid = threadIdx.x, lane = tid & 63, w = tid >> 6;
  const int l15 = lane & 15, q4 = lane >> 4;

  // permanent B-fragments: wave w owns gate w of slice j (32 gate rows, 2 tiles)
  short8 Bf[2][8];
#pragma unroll
  for (int tl = 0; tl < 2; ++tl) {
    int grow = w * 256 + j * 32 + tl * 16 + l15;
#pragma unroll
    for (int ks = 0; ks < 8; ++ks)
      Bf[tl][ks] = *(const short8*)(whh + (size_t)grow * 256 + ks * 32 + q4 * 8);
  }

  // zero hbuf: h_{-1} = 0 (sc==0 skips the consume phase)
  for (int i = tid; i < 32 * 132; i += 256) ((uint_t*)hbuf)[i] = 0u;

  float cst[4] = {0.f, 0.f, 0.f, 0.f};

  // xp: [t][g][b] layout, one u64 = 4 consecutive batches
  u64 xr64[2][2];
  auto ldxp = [&](int tt) {
#pragma unroll
    for (int mt = 0; mt < 2; ++mt)
#pragma unroll
      for (int tl = 0; tl < 2; ++tl) {
        int g = w * 256 + j * 32 + tl * 16 + l15;
        xr64[mt][tl] = *(const u64*)(xp + (size_t)tt * (GDIM * BATCH) + (size_t)g * 32 + mt * 16 + q4 * 4);
      }
  };

  const int cb  = tid >> 3;      // batch row (producer and consumer)
  const int cg0 = tid & 7;       // consumer col-slice (== producing WG j')
  const int c4  = (tid & 7) * 4; // producer first col (4 consecutive)

  ldxp((dir == 0) ? 0 : 1023);
  __syncthreads();

  for (int sc = 0; sc < 1024; ++sc) {
    const int tcur  = (dir == 0) ? sc : 1023 - sc;
    const int tnext = (dir == 0) ? (sc < 1023 ? sc + 1 : 1023) : (sc < 1023 ? 1022 - sc : 0);

    // ---- 1) fused consume: data + epoch spec-loaded together, ONE RT/iter ----
    if (sc > 0 && cg0 != j) {
      const u64 want = (u64)(unsigned)sc;
      const u64* ea = epochs + ((size_t)(dir * 2 + (sc & 1)) * 8 + cg0) * 16;
      const u64* rbuf = commd + (size_t)(sc & 1) * 2048 + (size_t)cb * 64 + cg0 * 8;
      u64 tmp[8];
      for (;;) {
#pragma unroll
        for (int k = 0; k < 8; ++k)
          tmp[k] = __hip_atomic_load(rbuf + k, __ATOMIC_RELAXED, __HIP_MEMORY_SCOPE_AGENT);
        u64 ev = __hip_atomic_load(ea, __ATOMIC_RELAXED, __HIP_MEMORY_SCOPE_AGENT);
        if (ev >= want) break;
      }
#pragma unroll
      for (int k = 0; k < 8; ++k)
        *(u64*)(hbuf + cb * 264 + cg0 * 32 + k * 4) = tmp[k];
    }

    // ---- 2) unpack xp[sc]: issued inside last publish's vm0 window, complete ----
    floatx4 acc[2][2];
#pragma unroll
    for (int mt = 0; mt < 2; ++mt)
#pragma unroll
      for (int tl = 0; tl < 2; ++tl) {
        u64 v = xr64[mt][tl];
#pragma unroll
        for (int rr = 0; rr < 4; ++rr)
          acc[mt][tl][rr] = bf2f((ushort_t)(v >> (16 * rr)));
      }

    lds_barrier();  // hbuf ready

    // ---- 3) gates = xp + h_{t-1} @ whh^T via MFMA ----
#pragma unroll
    for (int ks = 0; ks < 8; ++ks) {
      short8 a0 = *(const short8*)(hbuf + l15 * 264 + ks * 32 + q4 * 8);
      short8 a1 = *(const short8*)(hbuf + (16 + l15) * 264 + ks * 32 + q4 * 8);
      acc[0][0] = __builtin_amdgcn_mfma_f32_16x16x32_bf16(a0, Bf[0][ks], acc[0][0], 0, 0, 0);
      acc[0][1] = __builtin_amdgcn_mfma_f32_16x16x32_bf16(a0, Bf[1][ks], acc[0][1], 0, 0, 0);
      acc[1][0] = __builtin_amdgcn_mfma_f32_16x16x32_bf16(a1, Bf[0][ks], acc[1][0], 0, 0, 0);
      acc[1][1] = __builtin_amdgcn_mfma_f32_16x16x32_bf16(a1, Bf[1][ks], acc[1][1], 0, 0, 0);
    }

#pragma unroll
    for (int mt = 0; mt < 2; ++mt)
#pragma unroll
      for (int tl = 0; tl < 2; ++tl)
#pragma unroll
        for (int rr = 0; rr < 4; ++rr)
          stage[(mt * 16 + q4 * 4 + rr) * 133 + w * 32 + tl * 16 + l15] = acc[mt][tl][rr];
    lds_barrier();  // stage ready; still no vm drain

    // ---- elementwise LSTM cell: thread = (batch cb, cols c4..c4+3) ----
    float hv4[4];
#pragma unroll
    for (int i = 0; i < 4; ++i) {
      float gi = stage[cb * 133 +      c4 + i];
      float gf = stage[cb * 133 + 32 + c4 + i];
      float gg = stage[cb * 133 + 64 + c4 + i];
      float go = stage[cb * 133 + 96 + c4 + i];
      float c = sigf(gf) * cst[i] + sigf(gi) * tanh_f(gg);
      cst[i] = c;
      hv4[i] = sigf(go) * tanh_f(c);
    }
    u64 pv = (u64)f2bf(hv4[0]) | ((u64)f2bf(hv4[1]) << 16) |
             ((u64)f2bf(hv4[2]) << 32) | ((u64)f2bf(hv4[3]) << 48);

    // ---- 4) publish: stores -> ldxp(tnext) -> ONE vm0 -> barrier -> epoch ----
    __hip_atomic_store(commd + (size_t)((sc + 1) & 1) * 2048 + (size_t)cb * 64 + j * 8 + (tid & 7),
                       pv, __ATOMIC_RELAXED, __HIP_MEMORY_SCOPE_AGENT);
    *(u64*)(hbuf + cb * 264 + j * 32 + c4) = pv;  // own slice for next step's MFMA
    *(u64*)(hout + (size_t)tcur * (BATCH * 512) + cb * 512 + hoff + j * 32 + c4) = pv;
    ldxp(tnext);  // xp RT overlaps the store-ack drain below
    vm0();        // comm + hout + xp all drained together (~1 RT)
    __builtin_amdgcn_sched_barrier(0);
    __builtin_amdgcn_s_barrier();
    __builtin_amdgcn_sched_barrier(0);
    if (tid == 0)
      __hip_atomic_store(epochs + ((size_t)(dir * 2 + ((sc + 1) & 1)) * 8 + j) * 16,
                         (u64)(unsigned)(sc + 1), __ATOMIC_RELAXED, __HIP_MEMORY_SCOPE_AGENT);
    // next spin starts with a CLEAN vm queue: no hidden drain anywhere.
  }
}

// ---------------------------------------------------------------------------
// Attention scores -> e = exp(s - max_t s), per batch b.
// ---------------------------------------------------------------------------
__global__ __launch_bounds__(256) void attn_scores(
    const ushort_t* __restrict__ h1, const float* __restrict__ attn_w,
    const float* __restrict__ attn_b, float* __restrict__ e_out)
{
  const int b = blockIdx.x;
  __shared__ float sbuf[1024];
  __shared__ float red[4];
  const int tid = threadIdx.x, lane = tid & 63, w = tid >> 6;

  float wreg[8];
#pragma unroll
  for (int i = 0; i < 8; ++i) wreg[i] = attn_w[lane * 8 + i];

  for (int t = w; t < 1024; t += 4) {
    short8 hv = *(const short8*)(h1 + (size_t)t * (BATCH * 512) + b * 512 + lane * 8);
    float dot = 0.f;
#pragma unroll
    for (int i = 0; i < 8; ++i) dot += bf2fs(hv[i]) * wreg[i];
#pragma unroll
    for (int off = 32; off; off >>= 1) dot += __shfl_xor(dot, off);
    if (lane == 0) sbuf[t] = dot + attn_b[0];
  }
  __syncthreads();
  float m = -1e30f;
  for (int t = tid; t < 1024; t += 256) m = fmaxf(m, sbuf[t]);
#pragma unroll
  for (int off = 32; off; off >>= 1) m = fmaxf(m, __shfl_xor(m, off));
  if (lane == 0) red[w] = m;
  __syncthreads();
  float mm = fmaxf(fmaxf(red[0], red[1]), fmaxf(red[2], red[3]));
  for (int t = tid; t < 1024; t += 256) e_out[b * 1024 + t] = __expf(sbuf[t] - mm);
}

// ---------------------------------------------------------------------------
// Cumulative context: ctx[t][b][c] = (sum_{u<=t} e_u h_u[c]) / (sum e_u), bf16.
// ---------------------------------------------------------------------------
__global__ __launch_bounds__(256) void attn_ctx(
    const ushort_t* __restrict__ h1, const float* __restrict__ e_in, ushort_t* __restrict__ ctx)
{
  const int b = blockIdx.x >> 1, half = blockIdx.x & 1;
  const int c = half * 256 + threadIdx.x;
  float num = 0.f, den = 0.f;
  const ushort_t* hp = h1 + b * 512 + c;
  ushort_t* cp = ctx + b * 512 + c;
  const float* ep = e_in + b * 1024;
#pragma unroll 4
  for (int t = 0; t < 1024; ++t) {
    float ev = ep[t];
    float hv = bf2f(hp[(size_t)t * (BATCH * 512)]);
    num += ev * hv;
    den += ev;
    cp[(size_t)t * (BATCH * 512)] = f2bf(num / den);
  }
}

// ---------------------------------------------------------------------------
// casts
// ---------------------------------------------------------------------------
__global__ void castw(const float* __restrict__ in, ushort_t* __restrict__ out, int n) {
  int i = blockIdx.x * 256 + threadIdx.x;
  if (i < n) out[i] = f2bf(in[i]);
}
__global__ void castx(const float* __restrict__ x, ushort_t* __restrict__ xt) {
  int i = blockIdx.x * 256 + threadIdx.x;  // over 32768*128
  int dcol = i & 127;
  int m = i >> 7;
  int b = m & 31, s = m >> 5;
  xt[i] = f2bf(x[(size_t)b * (S_LEN * DIN) + s * DIN + dcol]);
}

extern "C" void kernel_launch(void* const* d_in, const int* in_sizes, int n_in,
                              void* d_out, int out_size, void* d_ws, size_t ws_size,
                              hipStream_t stream)
{
  const float* x     = (const float*)d_in[0];
  const float* wih0f = (const float*)d_in[1];
  const float* whh0f = (const float*)d_in[2];
  const float* b0f   = (const float*)d_in[3];
  const float* wih0b = (const float*)d_in[4];
  const float* whh0b = (const float*)d_in[5];
  const float* b0b   = (const float*)d_in[6];
  const float* wih1f = (const float*)d_in[7];
  const float* whh1f = (const float*)d_in[8];
  const float* b1f   = (const float*)d_in[9];
  const float* wih1b = (const float*)d_in[10];
  const float* whh1b = (const float*)d_in[11];
  const float* b1b   = (const float*)d_in[12];
  const float* attw  = (const float*)d_in[13];
  const float* attb  = (const float*)d_in[14];
  const float* headw = (const float*)d_in[15];
  const float* headb = (const float*)d_in[16];
  float* out = (float*)d_out;

  char* p = (char*)d_ws;
  auto alloc = [&](size_t bytes) {
    char* r = p;
    p += (bytes + 511) & ~(size_t)511;
    return r;
  };
  u64* ep0        = (u64*)alloc(512 * 8);   // layer-0 epochs (2 dir x 2 par x 8 j x 16 u64)
  u64* ep1        = (u64*)alloc(512 * 8);   // layer-1 epochs
  u64* comm0      = (u64*)alloc(8192 * 8);  // layer-0 data: 2 dir x 2 par x 2048 u64
  u64* comm1      = (u64*)alloc(8192 * 8);
  ushort_t* xt    = (ushort_t*)alloc((size_t)32768 * 128 * 2);
  ushort_t* cwih0f = (ushort_t*)alloc(131072 * 2);
  ushort_t* cwih0b = (ushort_t*)alloc(131072 * 2);
  ushort_t* cwhh0f = (ushort_t*)alloc(262144 * 2);
  ushort_t* cwhh0b = (ushort_t*)alloc(262144 * 2);
  ushort_t* cwih1f = (ushort_t*)alloc(524288 * 2);
  ushort_t* cwih1b = (ushort_t*)alloc(524288 * 2);
  ushort_t* cwhh1f = (ushort_t*)alloc(262144 * 2);
  ushort_t* cwhh1b = (ushort_t*)alloc(262144 * 2);
  ushort_t* cwhead = (ushort_t*)alloc(65536 * 2);
  ushort_t* xpA = (ushort_t*)alloc((size_t)32768 * 1024 * 2);
  ushort_t* xpB = (ushort_t*)alloc((size_t)32768 * 1024 * 2);
  ushort_t* h0  = (ushort_t*)alloc((size_t)32768 * 512 * 2);
  ushort_t* h1  = (ushort_t*)alloc((size_t)32768 * 512 * 2);
  float* ebuf   = (float*)alloc(32 * 1024 * 4);
  ushort_t* ctx = xpA;  // reuse (xp dead by then)

  (void)in_sizes; (void)n_in; (void)out_size; (void)ws_size;

  // zero both layers' epoch arrays (data words are epoch-gated; no init needed)
  (void)hipMemsetAsync(ep0, 0, 2 * 512 * 8, stream);

  castw<<<512, 256, 0, stream>>>(wih0f, cwih0f, 131072);
  castw<<<512, 256, 0, stream>>>(wih0b, cwih0b, 131072);
  castw<<<1024, 256, 0, stream>>>(whh0f, cwhh0f, 262144);
  castw<<<1024, 256, 0, stream>>>(whh0b, cwhh0b, 262144);
  castw<<<2048, 256, 0, stream>>>(wih1f, cwih1f, 524288);
  castw<<<2048, 256, 0, stream>>>(wih1b, cwih1b, 524288);
  castw<<<1024, 256, 0, stream>>>(whh1f, cwhh1f, 262144);
  castw<<<1024, 256, 0, stream>>>(whh1b, cwhh1b, 262144);
  castw<<<256, 256, 0, stream>>>(headw, cwhead, 65536);
  castx<<<16384, 256, 0, stream>>>(x, xt);

  // layer 0: xp in transposed [t][g][b] layout (mode 2)
  gemm_bf16<<<dim3(8, 256), 256, 0, stream>>>(xt, cwih0f, b0f, xpA, 32768, 1024, 128, 2);
  gemm_bf16<<<dim3(8, 256), 256, 0, stream>>>(xt, cwih0b, b0b, xpB, 32768, 1024, 128, 2);
  lstm_layer<<<16, 256, 0, stream>>>(xpA, xpB, cwhh0f, cwhh0b, h0, comm0, ep0);

  // layer 1
  gemm_bf16<<<dim3(8, 256), 256, 0, stream>>>(h0, cwih1f, b1f, xpA, 32768, 1024, 512, 2);
  gemm_bf16<<<dim3(8, 256), 256, 0, stream>>>(h0, cwih1b, b1b, xpB, 32768, 1024, 512, 2);
  lstm_layer<<<16, 256, 0, stream>>>(xpA, xpB, cwhh1f, cwhh1b, h1, comm1, ep1);

  // attention + head
  attn_scores<<<32, 256, 0, stream>>>(h1, attw, attb, ebuf);
  attn_ctx<<<64, 256, 0, stream>>>(h1, ebuf, ctx);
  gemm_bf16<<<dim3(1, 256), 256, 0, stream>>>(ctx, cwhead, headb, out, 32768, 128, 512, 1);
}